// Round 9
// baseline (318.219 us; speedup 1.0000x reference)
//
#include <hip/hip_runtime.h>
#include <hip/hip_bf16.h>
#include <stdint.h>

#define MM 16384
#define DD 256
#define HH 4
#define KK 16
#define DFF_ 1024

typedef __attribute__((ext_vector_type(8))) short bf16x8;
typedef __attribute__((ext_vector_type(16))) float f32x16;
typedef __attribute__((ext_vector_type(2))) float f32x2;

__device__ __forceinline__ unsigned short f2bf(float f) {
    unsigned u = __builtin_bit_cast(unsigned, f);
    unsigned r = u + 0x7fffu + ((u >> 16) & 1u);
    return (unsigned short)(r >> 16);
}
__device__ __forceinline__ float bf2f(unsigned short h) {
    unsigned u = ((unsigned)h) << 16;
    return __builtin_bit_cast(float, u);
}

__device__ __forceinline__ void gload_lds16(const void* g, void* l) {
    __builtin_amdgcn_global_load_lds(
        (const __attribute__((address_space(1))) unsigned int*)g,
        (__attribute__((address_space(3))) unsigned int*)l, 16, 0, 0);
}

template <int N> __device__ __forceinline__ void waitv() {
    asm volatile("s_waitcnt vmcnt(%0)" :: "n"(N) : "memory");
}

// ---------------------------------------------------------------------------
// Fragment layouts (bf16, 16B chunks of 8 elems):
// A-frag (row m, k):  chunk = ((m>>5)*(KD/16) + (k>>4))*64 + ((k>>3)&1)*32 + (m&31), elem = k&7
// B-frag (col n, k):  same with n.
// v_mfma_f32_32x32x16_bf16 C/D: col=lane&31, row=(reg&3)+8*(reg>>2)+4*(lane>>5)
// kv buffer: fp8 e4m3 rows of 512 B, groups of 8 B = [K4 | V4].
// NOTE (R10): gemm_ln fusion; R14: grid-starvation lever (335.7->311.8).
// NOTE (R15): 32-col wave tiles from VMEM regress (A-traffic doubles).
// NOTE (R16): FFN1 4x residency: no effect -> latency-bound, limited by
//   BYTES IN FLIGHT (~1KB/wg) vs ~600cyc L3 latency; 1MB/CU traffic ~= 40us.
// NOTE (R17): 2-phase pipeline, 16 loads/wave in flight = SAME depth: flat.
// NOTE (R18/this round): FFN1 full-K prestage: 128KB LDS (1 wg/CU, 8 waves),
//   ALL 16 gload_lds/wave issued up-front in chunk order -> 128KB in flight
//   per CU (64x), counted vmcnt(12/8/4/0) + raw s_barrier per chunk, compute
//   overlaps remaining staging. L2-BW floor ~7.5us. This is R11's geometry
//   minus its failure causes (per-chunk vmcnt(0) full drain, no overlap).
// ---------------------------------------------------------------------------

// wfrag layout (shorts): WQF@0 (blk stride 65536), KVF@131072 (131072),
//   WOF@393216 (65536), W1F@524288 (262144), W2F@1048576 (262144)
__global__ __launch_bounds__(256) void prep_weights(
        const float* __restrict__ Wq, const float* __restrict__ Wk,
        const float* __restrict__ Wv, const float* __restrict__ Wo,
        const float* __restrict__ W1, const float* __restrict__ W2,
        unsigned short* __restrict__ wf) {
    int t = blockIdx.x * blockDim.x + threadIdx.x;
    const float* src; unsigned short* dst;
    int kd, lg, rem, blk, e, sect;
    if (t < 131072) { sect = 0; rem = t; blk = rem >> 16; e = rem & 65535;
        src = Wq; dst = wf + blk * 65536; kd = 256; lg = 8; }
    else if (t < 262144) { sect = 1; rem = t - 131072; blk = rem >> 16; e = rem & 65535;
        src = Wk; dst = wf + 131072 + blk * 131072; kd = 256; lg = 8; }
    else if (t < 393216) { sect = 2; rem = t - 262144; blk = rem >> 16; e = rem & 65535;
        src = Wv; dst = wf + 131072 + blk * 131072; kd = 256; lg = 8; }
    else if (t < 524288) { sect = 0; rem = t - 393216; blk = rem >> 16; e = rem & 65535;
        src = Wo; dst = wf + 393216 + blk * 65536; kd = 256; lg = 8; }
    else if (t < 1048576) { sect = 0; rem = t - 524288; blk = rem >> 18; e = rem & 262143;
        src = W1; dst = wf + 524288 + blk * 262144; kd = 256; lg = 10; }
    else if (t < 1572864) { sect = 0; rem = t - 1048576; blk = rem >> 18; e = rem & 262143;
        src = W2; dst = wf + 1048576 + blk * 262144; kd = 1024; lg = 8; }
    else return;
    int k = e >> lg;
    int n = e & ((1 << lg) - 1);
    if (sect == 1) n = (n >> 2) * 8 + (n & 3);
    else if (sect == 2) n = (n >> 2) * 8 + 4 + (n & 3);
    float v = src[(size_t)blk * kd * (1 << lg) + e];
    int off = ((n >> 5) * (kd >> 4) + (k >> 4)) * 512 + (((k >> 3) & 1) * 32 + (n & 31)) * 8 + (k & 7);
    dst[off] = f2bf(v);
}

// 3 slices in one launch: y=0: LN(xa,g,b)->outln; y=1: conv(xa)->outca; y=2: conv(xb)->outcb
__global__ __launch_bounds__(256) void ln3_to_frag(
        const float* __restrict__ xa, const float* __restrict__ g,
        const float* __restrict__ b, const float* __restrict__ xb,
        unsigned short* __restrict__ outln, unsigned short* __restrict__ outca,
        unsigned short* __restrict__ outcb) {
    int y = blockIdx.y;
    const float* x = (y == 2) ? xb : xa;
    unsigned short* out = (y == 0) ? outln : (y == 1 ? outca : outcb);
    int apply_ln = (y == 0);
    int wave = threadIdx.x >> 6, lane = threadIdx.x & 63;
    int m = blockIdx.x * 4 + wave;
    const float4 xv = reinterpret_cast<const float4*>(x + (size_t)m * DD)[lane];
    float vals[4] = {xv.x, xv.y, xv.z, xv.w};
    int k0 = lane * 4;
    if (apply_ln) {
        float s = vals[0] + vals[1] + vals[2] + vals[3];
        float sq = vals[0]*vals[0] + vals[1]*vals[1] + vals[2]*vals[2] + vals[3]*vals[3];
        for (int o = 32; o; o >>= 1) { s += __shfl_xor(s, o, 64); sq += __shfl_xor(sq, o, 64); }
        float mean = s * (1.0f / DD);
        float var = sq * (1.0f / DD) - mean * mean;
        float rs = rsqrtf(var + 1e-5f);
        #pragma unroll
        for (int c = 0; c < 4; ++c)
            vals[c] = (vals[c] - mean) * rs * g[k0 + c] + b[k0 + c];
    }
    int chunk = ((m >> 5) * (DD >> 4) + (k0 >> 4)) * 64 + ((k0 >> 3) & 1) * 32 + (m & 31);
    ushort4 o4 = make_ushort4(f2bf(vals[0]), f2bf(vals[1]), f2bf(vals[2]), f2bf(vals[3]));
    *reinterpret_cast<ushort4*>(out + (size_t)chunk * 8 + (k0 & 7)) = o4;
}

template <int KG>
__device__ __forceinline__ void compute_tile(
        const bf16x8* __restrict__ a0, const bf16x8* __restrict__ a1,
        const bf16x8* __restrict__ b0, const bf16x8* __restrict__ b1,
        f32x16 acc[2][2]) {
    #pragma unroll 4
    for (int g = 0; g < KG; ++g) {
        bf16x8 av0 = a0[g * 64];
        bf16x8 av1 = a1[g * 64];
        bf16x8 bv0 = b0[g * 64];
        bf16x8 bv1 = b1[g * 64];
        acc[0][0] = __builtin_amdgcn_mfma_f32_32x32x16_bf16(av0, bv0, acc[0][0], 0, 0, 0);
        acc[0][1] = __builtin_amdgcn_mfma_f32_32x32x16_bf16(av0, bv1, acc[0][1], 0, 0, 0);
        acc[1][0] = __builtin_amdgcn_mfma_f32_32x32x16_bf16(av1, bv0, acc[1][0], 0, 0, 0);
        acc[1][1] = __builtin_amdgcn_mfma_f32_32x32x16_bf16(av1, bv1, acc[1][1], 0, 0, 0);
    }
}

// R18: FFN1 + GELU, FULL-K prestage. wg = 128x128 tile, 512 thr / 8 waves
// (4m x 2n of 32x64). LDS 128KB = A[64KB] | B[64KB], linear frag-block copy
// (seg s<64: A block (g=s>>4, kg=s&15); s>=64: B likewise). Each wave issues
// its 16 gload_lds up-front in CHUNK ORDER (4 per BK=64 chunk), then per
// chunk: counted vmcnt + s_barrier + 8 MFMA from LDS.
__global__ __launch_bounds__(512) void gemm_gelu_deep(
        const char* __restrict__ A, const char* __restrict__ B,
        unsigned short* __restrict__ outp, const float* __restrict__ bias,
        int out_kd) {
    constexpr int KG = 16;
    __shared__ alignas(16) char smem[131072];
    int wave = threadIdx.x >> 6, lane = threadIdx.x & 63;
    int wm = wave >> 1, wn = wave & 1;       // 4m x 2n: tile 32 x 64
    int m0 = blockIdx.x * 128, n0 = blockIdx.y * 128;

    // stage: wave w handles t = w*4+i (i=0..3) per chunk; t<16 -> A, else B.
    #pragma unroll
    for (int c = 0; c < 4; ++c) {
        #pragma unroll
        for (int i = 0; i < 4; ++i) {
            int t = wave * 4 + i;
            const char* gsrc; int s;
            if (t < 16) {
                int g = t >> 2; int kg = 4 * c + (t & 3);
                s = g * 16 + kg;
                gsrc = A + ((((size_t)(m0 >> 5) + g) * 16 + kg) << 10);
            } else {
                int u = t - 16; int g = u >> 2; int kg = 4 * c + (u & 3);
                s = 64 + g * 16 + kg;
                gsrc = B + ((((size_t)(n0 >> 5) + g) * 16 + kg) << 10);
            }
            gload_lds16(gsrc + lane * 16, smem + ((size_t)s << 10));
        }
    }

    const bf16x8* lA  = (const bf16x8*)smem + (wm * 16) * 64 + lane;
    const bf16x8* lB0 = (const bf16x8*)(smem + 65536) + (wn * 2 * 16) * 64 + lane;
    const bf16x8* lB1 = lB0 + 16 * 64;
    f32x16 acc[2] = {};

    #define CHUNK(c, V)                                                         \
        waitv<V>();                                                             \
        __builtin_amdgcn_s_barrier();                                           \
        _Pragma("unroll")                                                       \
        for (int kg = 4 * (c); kg < 4 * (c) + 4; ++kg) {                        \
            bf16x8 av  = lA[kg * 64];                                           \
            bf16x8 bv0 = lB0[kg * 64];                                          \
            bf16x8 bv1 = lB1[kg * 64];                                          \
            acc[0] = __builtin_amdgcn_mfma_f32_32x32x16_bf16(av, bv0, acc[0], 0, 0, 0); \
            acc[1] = __builtin_amdgcn_mfma_f32_32x32x16_bf16(av, bv1, acc[1], 0, 0, 0); \
        }
    CHUNK(0, 12)
    CHUNK(1, 8)
    CHUNK(2, 4)
    CHUNK(3, 0)
    #undef CHUNK

    __builtin_amdgcn_s_barrier();   // all LDS reads done; safe to overlay pads

    // epilogue: GELU -> bf16 A-frag; wave-private pad-33 tiles in smem.
    int mw = m0 + wm * 32, nw = n0 + wn * 64;
    int col = lane & 31, rq = (lane >> 5) * 4;
    float* wlds = (float*)smem + wave * 1056;
    for (int j = 0; j < 2; ++j) {
        #pragma unroll
        for (int r = 0; r < 16; ++r) {
            int row = (r & 3) + 8 * (r >> 2) + rq;
            int n = nw + j * 32 + col;
            float v = acc[j][r] + bias[n];
            float arg = v * (1.5957691216f + 0.0713548163f * v * v);
            v = v * __frcp_rn(1.0f + __expf(-arg));
            wlds[row * 33 + col] = v;
        }
        #pragma unroll
        for (int it = 0; it < 2; ++it) {
            int task = lane + it * 64;
            int row = task >> 2, cc = task & 3;
            int m = mw + row;
            int k = nw + j * 32 + cc * 8;
            float* p = &wlds[row * 33 + cc * 8];
            unsigned short us[8];
            #pragma unroll
            for (int e = 0; e < 8; ++e) us[e] = f2bf(p[e]);
            int chunk = ((m >> 5) * (out_kd >> 4) + (k >> 4)) * 64 + ((k >> 3) & 1) * 32 + (m & 31);
            reinterpret_cast<uint4*>(outp)[chunk] = *reinterpret_cast<uint4*>(us);
        }
    }
}

// R14 form: final FFN2. 64x128 wg tile, 4 waves = 2m x 2n of 32x64 each.
template <int KD, int NOUT, bool RESID, bool BIAS>
__global__ __launch_bounds__(256) void gemm_frag64(
        const bf16x8* __restrict__ A, const bf16x8* __restrict__ B,
        float* __restrict__ outp, const float* __restrict__ resid,
        const float* __restrict__ bias) {
    constexpr int KG = KD / 16;
    int wave = threadIdx.x >> 6, lane = threadIdx.x & 63;
    int wm = wave & 1, wn = wave >> 1;
    int mw = blockIdx.x * 64 + wm * 32;
    int nw = blockIdx.y * 128 + wn * 64;
    const bf16x8* a0 = A + ((size_t)(mw >> 5) * KG) * 64 + lane;
    const bf16x8* b0 = B + ((size_t)(nw >> 5) * KG) * 64 + lane;
    const bf16x8* b1 = b0 + (size_t)KG * 64;
    f32x16 acc[2] = {};
    #pragma unroll 4
    for (int g = 0; g < KG; ++g) {
        bf16x8 av = a0[g * 64];
        bf16x8 bv0 = b0[g * 64];
        bf16x8 bv1 = b1[g * 64];
        acc[0] = __builtin_amdgcn_mfma_f32_32x32x16_bf16(av, bv0, acc[0], 0, 0, 0);
        acc[1] = __builtin_amdgcn_mfma_f32_32x32x16_bf16(av, bv1, acc[1], 0, 0, 0);
    }
    int col = lane & 31, rq = (lane >> 5) * 4;
    #pragma unroll
    for (int j = 0; j < 2; ++j) {
        #pragma unroll
        for (int r = 0; r < 16; ++r) {
            int row = (r & 3) + 8 * (r >> 2) + rq;
            int m = mw + row;
            int n = nw + j * 32 + col;
            float v = acc[j][r];
            if (BIAS) v += bias[n];
            if (RESID) v += resid[(size_t)m * NOUT + n];
            outp[(size_t)m * NOUT + n] = v;
        }
    }
}

// R14/R10 form: fused Q + KV projections, 128x128 wg tiles, direct loads.
__global__ __launch_bounds__(256) void gemm_qkv(
        const bf16x8* __restrict__ Aq, const bf16x8* __restrict__ Akv,
        const bf16x8* __restrict__ Bq, const bf16x8* __restrict__ Bkv,
        unsigned short* __restrict__ qout, unsigned char* __restrict__ kvout) {
    constexpr int KG = 16;
    int wave = threadIdx.x >> 6, lane = threadIdx.x & 63;
    int wm = wave & 1, wn = wave >> 1;
    int y = blockIdx.y;
    bool isQ = y < 2;
    const bf16x8* A = isQ ? Aq : Akv;
    const bf16x8* B = isQ ? Bq : Bkv;
    int n0 = (isQ ? y : y - 2) * 128 + wn * 64;
    int m0 = blockIdx.x * 128 + wm * 64;
    const bf16x8* a0 = A + ((size_t)(m0 >> 5) * KG) * 64 + lane;
    const bf16x8* a1 = a0 + (size_t)KG * 64;
    const bf16x8* b0 = B + ((size_t)(n0 >> 5) * KG) * 64 + lane;
    const bf16x8* b1 = b0 + (size_t)KG * 64;
    f32x16 acc[2][2] = {};
    compute_tile<KG>(a0, a1, b0, b1, acc);
    int col = lane & 31, rq = (lane >> 5) * 4;
    #pragma unroll
    for (int i = 0; i < 2; ++i)
    #pragma unroll
    for (int j = 0; j < 2; ++j)
    #pragma unroll
    for (int r = 0; r < 16; ++r) {
        int row = (r & 3) + 8 * (r >> 2) + rq;
        int m = m0 + i * 32 + row;
        int n = n0 + j * 32 + col;
        float v = acc[i][j][r];
        if (isQ) qout[(size_t)m * 256 + n] = f2bf(v);
        else kvout[(size_t)m * 512 + n] =
            (unsigned char)(__builtin_amdgcn_cvt_pk_fp8_f32(v, v, 0, false) & 0xff);
    }
}

// butterfly reduce-scatter stage: N slots -> N/2 slots (xor-butterfly).
template <int O, int N>
__device__ __forceinline__ void redstage(float* a, int lane) {
    int sel = lane & O;
    #pragma unroll
    for (int u = 0; u < N / 2; ++u) {
        float lo = a[2 * u], hi = a[2 * u + 1];
        float keep = sel ? hi : lo;
        float send = sel ? lo : hi;
        a[u] = keep + __shfl_xor(send, O, 64);
    }
}

// R14 form: Fused GEMM(+bias)+resid -> f32 C; LayerNorm rows -> bf16 A-frag.
// wg = 64 rows x 256 cols with 8 waves (512 thr), 2m x 4n of 32x64.
template <int KD, bool BIAS>
__global__ __launch_bounds__(512) void gemm_ln(
        const bf16x8* __restrict__ A, const bf16x8* __restrict__ B,
        float* __restrict__ out_f32, const float* __restrict__ resid,
        const float* __restrict__ bias,
        const float* __restrict__ lng, const float* __restrict__ lnb,
        unsigned short* __restrict__ out_frag) {
    constexpr int KG = KD / 16;
    __shared__ float pstat[4][64][2];   // [wn][block row][sum,sumsq]
    __shared__ float stats[64][2];      // [block row][mean, rstd]
    __shared__ float tlds[8][32 * 33];  // per-wave transpose pads
    int wave = threadIdx.x >> 6, lane = threadIdx.x & 63;
    int wm = wave >> 2, wn = wave & 3;
    int m0 = blockIdx.x * 64;
    int mw = m0 + wm * 32;
    int n0 = wn * 64;
    const bf16x8* a0 = A + ((size_t)(mw >> 5) * KG) * 64 + lane;
    const bf16x8* b0 = B + ((size_t)(n0 >> 5) * KG) * 64 + lane;
    const bf16x8* b1 = b0 + (size_t)KG * 64;
    f32x16 acc[2] = {};
    #pragma unroll 4
    for (int g = 0; g < KG; ++g) {
        bf16x8 av = a0[g * 64];
        bf16x8 bv0 = b0[g * 64];
        bf16x8 bv1 = b1[g * 64];
        acc[0] = __builtin_amdgcn_mfma_f32_32x32x16_bf16(av, bv0, acc[0], 0, 0, 0);
        acc[1] = __builtin_amdgcn_mfma_f32_32x32x16_bf16(av, bv1, acc[1], 0, 0, 0);
    }
    int col = lane & 31, rq = (lane >> 5) * 4;

    // epilogue pass 1: v = acc (+bias) + resid; write f32; stash v in acc.
    #pragma unroll
    for (int j = 0; j < 2; ++j) {
        #pragma unroll
        for (int r = 0; r < 16; ++r) {
            int row = (r & 3) + 8 * (r >> 2) + rq;
            int m = mw + row;
            int n = n0 + j * 32 + col;
            float v = acc[j][r];
            if (BIAS) v += bias[n];
            v += resid[(size_t)m * DD + n];
            out_f32[(size_t)m * DD + n] = v;
            acc[j][r] = v;
        }
    }

    // per-wave row sums over this wave's 64 cols (16 slots, 4 stages + xor16).
    {
        float ps[16];
        #pragma unroll
        for (int r = 0; r < 16; ++r)
            ps[r] = acc[0][r] + acc[1][r];
        redstage<1, 16>(ps, lane);
        redstage<2, 8>(ps, lane);
        redstage<4, 4>(ps, lane);
        redstage<8, 2>(ps, lane);
        float sum64 = ps[0] + __shfl_xor(ps[0], 16, 64);
        float qs[16];
        #pragma unroll
        for (int r = 0; r < 16; ++r) {
            float a = acc[0][r], b = acc[1][r];
            qs[r] = a * a + b * b;
        }
        redstage<1, 16>(qs, lane);
        redstage<2, 8>(qs, lane);
        redstage<4, 4>(qs, lane);
        redstage<8, 2>(qs, lane);
        float sq64 = qs[0] + __shfl_xor(qs[0], 16, 64);
        int slot = lane & 15;
        int ROW = wm * 32 + (slot & 3) + 8 * (slot >> 2) + rq;
        if ((lane & 16) == 0)
            *reinterpret_cast<float2*>(&pstat[wn][ROW][0]) = make_float2(sum64, sq64);
    }
    __syncthreads();
    if (threadIdx.x < 64) {
        int R = threadIdx.x;
        float s = 0.0f, sq = 0.0f;
        #pragma unroll
        for (int w = 0; w < 4; ++w) {
            float2 p = *reinterpret_cast<float2*>(&pstat[w][R][0]);
            s += p.x; sq += p.y;
        }
        float mean = s * (1.0f / DD);
        float var = sq * (1.0f / DD) - mean * mean;
        float rstd = rsqrtf(var + 1e-5f);
        *reinterpret_cast<float2*>(&stats[R][0]) = make_float2(mean, rstd);
    }
    __syncthreads();

    // normalize + transpose-pack to frags (pad-33 wave-private tiles).
    float* wlds = &tlds[wave][0];
    float mean_r[16], rstd_r[16];
    #pragma unroll
    for (int r = 0; r < 16; ++r) {
        int row = (r & 3) + 8 * (r >> 2) + rq;
        float2 st = *reinterpret_cast<float2*>(&stats[wm * 32 + row][0]);
        mean_r[r] = st.x; rstd_r[r] = st.y;
    }
    for (int j = 0; j < 2; ++j) {
        float gj = lng[n0 + j * 32 + col];
        float bj = lnb[n0 + j * 32 + col];
        #pragma unroll
        for (int r = 0; r < 16; ++r) {
            int row = (r & 3) + 8 * (r >> 2) + rq;
            float v = (acc[j][r] - mean_r[r]) * rstd_r[r] * gj + bj;
            wlds[row * 33 + col] = v;
        }
        #pragma unroll
        for (int it = 0; it < 2; ++it) {
            int task = lane + it * 64;
            int row = task >> 2, cc = task & 3;
            int m = mw + row;
            int k = n0 + j * 32 + cc * 8;
            float* p = &wlds[row * 33 + cc * 8];
            unsigned short us[8];
            #pragma unroll
            for (int e = 0; e < 8; ++e) us[e] = f2bf(p[e]);
            int chunk = ((m >> 5) * (DD >> 4) + (k >> 4)) * 64 + ((k >> 3) & 1) * 32 + (m & 31);
            *reinterpret_cast<uint4*>(out_frag + (size_t)chunk * 8) = *reinterpret_cast<uint4*>(us);
        }
    }
}

// One wave per point. lane = h*16+s; dims d0 = h*64+s*4.
// Distributed scores; pe handled algebraically. kv rows: 512 B fp8.
// R12: score reduction via butterfly reduce-scatter (15 shfl vs 64).
__global__ __launch_bounds__(256) void attn_kernel(
        const unsigned short* __restrict__ q, const unsigned char* __restrict__ kv,
        const float* __restrict__ coord, const float* __restrict__ ctx_coord,
        const int* __restrict__ knn,
        const float* __restrict__ pe_w, const float* __restrict__ pe_b,
        unsigned short* __restrict__ out_frag) {
    int wave = threadIdx.x >> 6, lane = threadIdx.x & 63;
    int m = blockIdx.x * 4 + wave;
    int s = lane & 15;
    int d0 = (lane >> 4) * 64 + s * 4;

    ushort4 qv4 = *reinterpret_cast<const ushort4*>(q + (size_t)m * DD + d0);
    float qx = bf2f(qv4.x), qy = bf2f(qv4.y), qz = bf2f(qv4.z), qw = bf2f(qv4.w);
    float4 pw0 = *reinterpret_cast<const float4*>(pe_w + d0);
    float4 pw1 = *reinterpret_cast<const float4*>(pe_w + DD + d0);
    float4 pw2 = *reinterpret_cast<const float4*>(pe_w + 2 * DD + d0);
    float4 pbv = *reinterpret_cast<const float4*>(pe_b + d0);

    float cx = coord[m * 3], cy = coord[m * 3 + 1], cz = coord[m * 3 + 2];
    int myidx = knn[(size_t)m * KK + s];
    int icm = myidx < 0 ? 0 : myidx;
    float rx = cx - ctx_coord[icm * 3];
    float ry = cy - ctx_coord[icm * 3 + 1];
    float rz = cz - ctx_coord[icm * 3 + 2];

    float t0 = qx * pw0.x + qy * pw0.y + qz * pw0.z + qw * pw0.w;
    float t1 = qx * pw1.x + qy * pw1.y + qz * pw1.z + qw * pw1.w;
    float t2 = qx * pw2.x + qy * pw2.y + qz * pw2.z + qw * pw2.w;
    float t3 = qx * pbv.x + qy * pbv.y + qz * pbv.z + qw * pbv.w;
    #pragma unroll
    for (int o = 1; o < 16; o <<= 1) {
        t0 += __shfl_xor(t0, o, 64);
        t1 += __shfl_xor(t1, o, 64);
        t2 += __shfl_xor(t2, o, 64);
        t3 += __shfl_xor(t3, o, 64);
    }

    // per-lane partials for all 16 scores, then one butterfly reduce-scatter
    float P[KK];
    unsigned vpk[KK];
    #pragma unroll
    for (int j = 0; j < KK; ++j) {
        int ij = __shfl(myidx, j, 64);
        int ic = ij < 0 ? 0 : ij;
        uint2 kvv = *reinterpret_cast<const uint2*>(kv + (size_t)ic * 512 + (d0 >> 2) * 8);
        vpk[j] = kvv.y;
        f32x2 k01 = __builtin_amdgcn_cvt_pk_f32_fp8(kvv.x, false);
        f32x2 k23 = __builtin_amdgcn_cvt_pk_f32_fp8(kvv.x, true);
        P[j] = qx * k01.x + qy * k01.y + qz * k23.x + qw * k23.y;
    }
    redstage<1, 16>(P, lane);
    redstage<2, 8>(P, lane);
    redstage<4, 4>(P, lane);
    redstage<8, 2>(P, lane);
    float corr = rx * t0 + ry * t1 + rz * t2 + t3;
    float sc_own = (myidx >= 0) ? (P[0] + corr) * 0.125f : -1e9f;

    float mx = sc_own;
    mx = fmaxf(mx, __shfl_xor(mx, 1, 64));
    mx = fmaxf(mx, __shfl_xor(mx, 2, 64));
    mx = fmaxf(mx, __shfl_xor(mx, 4, 64));
    mx = fmaxf(mx, __shfl_xor(mx, 8, 64));
    float e = __expf(sc_own - mx);
    float sum = e;
    sum += __shfl_xor(sum, 1, 64);
    sum += __shfl_xor(sum, 2, 64);
    sum += __shfl_xor(sum, 4, 64);
    sum += __shfl_xor(sum, 8, 64);
    float w_own = e * __frcp_rn(sum);

    float wrx = w_own * rx, wry = w_own * ry, wrz = w_own * rz;
    #pragma unroll
    for (int o = 1; o < 16; o <<= 1) {
        wrx += __shfl_xor(wrx, o, 64);
        wry += __shfl_xor(wry, o, 64);
        wrz += __shfl_xor(wrz, o, 64);
    }

    int gbase = lane & 48;
    float ax = 0.f, ay = 0.f, az = 0.f, aw = 0.f;
    #pragma unroll
    for (int j = 0; j < KK; ++j) {
        float wj = __shfl(w_own, gbase + j, 64);
        f32x2 v01 = __builtin_amdgcn_cvt_pk_f32_fp8(vpk[j], false);
        f32x2 v23 = __builtin_amdgcn_cvt_pk_f32_fp8(vpk[j], true);
        ax += wj * v01.x;
        ay += wj * v01.y;
        az += wj * v23.x;
        aw += wj * v23.y;
    }
    ax += wrx * pw0.x + wry * pw1.x + wrz * pw2.x + pbv.x;
    ay += wrx * pw0.y + wry * pw1.y + wrz * pw2.y + pbv.y;
    az += wrx * pw0.z + wry * pw1.z + wrz * pw2.z + pbv.z;
    aw += wrx * pw0.w + wry * pw1.w + wrz * pw2.w + pbv.w;

    ushort4 o4 = make_ushort4(f2bf(ax), f2bf(ay), f2bf(az), f2bf(aw));
    int chunk = ((m >> 5) * (DD >> 4) + (d0 >> 4)) * 64 + ((d0 >> 3) & 1) * 32 + (m & 31);
    *reinterpret_cast<ushort4*>(out_frag + (size_t)chunk * 8 + (d0 & 7)) = o4;
}

extern "C" void kernel_launch(void* const* d_in, const int* in_sizes, int n_in,
                              void* d_out, int out_size, void* d_ws, size_t ws_size,
                              hipStream_t stream) {
    const float* feat_a = (const float*)d_in[0];
    const float* coord_a = (const float*)d_in[1];
    const float* feat_b = (const float*)d_in[2];
    const float* coord_b = (const float*)d_in[3];
    const float* Wq = (const float*)d_in[4];
    const float* Wk = (const float*)d_in[5];
    const float* Wv = (const float*)d_in[6];
    const float* Wo = (const float*)d_in[7];
    const float* ln1_g = (const float*)d_in[8];
    const float* ln1_b = (const float*)d_in[9];
    const float* pe_w = (const float*)d_in[10];
    const float* pe_b = (const float*)d_in[11];
    const float* W1 = (const float*)d_in[12];
    const float* b1 = (const float*)d_in[13];
    const float* W2 = (const float*)d_in[14];
    const float* b2 = (const float*)d_in[15];
    const float* ln2_g = (const float*)d_in[16];
    const float* ln2_b = (const float*)d_in[17];
    const int* knn_a2a = (const int*)d_in[18];
    const int* knn_a2b = (const int*)d_in[19];

    char* ws = (char*)d_ws;
    unsigned short* wfrag = (unsigned short*)ws;                  // 3 MB (4 MB region)
    float* xmid = (float*)(ws + (4ull << 20));                    // 16 MB
    float* xout0 = (float*)(ws + (20ull << 20));                  // 16 MB
    unsigned short* qbuf = (unsigned short*)(ws + (36ull << 20)); // 8 MB
    unsigned char* kvbuf = (unsigned char*)(ws + (52ull << 20));  // 8 MB (fp8)
    unsigned short* xnf = (unsigned short*)(ws + (68ull << 20));  // 8 MB
    unsigned short* ctxfa = (unsigned short*)(ws + (76ull << 20));// 8 MB
    unsigned short* attnf = (unsigned short*)(ws + (84ull << 20));// 8 MB
    unsigned short* ctxfb = (unsigned short*)(ws + (92ull << 20));// 8 MB -> 100 MB
    unsigned short* geluf = (unsigned short*)(ws + (36ull << 20));// 32 MB, overlays q/kv (dead by FFN)

    const unsigned short* WQF = wfrag;
    const unsigned short* KVF = wfrag + 131072;
    const unsigned short* WOF = wfrag + 393216;
    const unsigned short* W1F = wfrag + 524288;
    const unsigned short* W2F = wfrag + 1048576;

    prep_weights<<<(1572864 + 255) / 256, 256, 0, stream>>>(Wq, Wk, Wv, Wo, W1, W2, wfrag);

    // one launch: xnf = LN1(feat_a); ctxfa = conv(feat_a); ctxfb = conv(feat_b)
    ln3_to_frag<<<dim3(MM / 4, 3), 256, 0, stream>>>(feat_a, ln1_g, ln1_b, feat_b,
                                                     xnf, ctxfa, ctxfb);

    // ---- block 0: self(a) ----
    gemm_qkv<<<dim3(MM / 128, 6), 256, 0, stream>>>(
        (const bf16x8*)xnf, (const bf16x8*)ctxfa,
        (const bf16x8*)WQF, (const bf16x8*)KVF, qbuf, kvbuf);

    attn_kernel<<<MM / 4, 256, 0, stream>>>(qbuf, kvbuf, coord_a, coord_a, knn_a2a,
                                            pe_w, pe_b, attnf);

    // Wo-GEMM + resid + LN2 -> xmid (f32) and xnf (frags)
    gemm_ln<256, false><<<MM / 64, 512, 0, stream>>>(
        (const bf16x8*)attnf, (const bf16x8*)WOF, xmid, feat_a, nullptr,
        ln2_g, ln2_b, xnf);

    // FFN1+GELU: full-K prestage, 128x128 tiles, 8 waves, grid (128,8)
    gemm_gelu_deep<<<dim3(MM / 128, 8), 512, 0, stream>>>(
        (const char*)xnf, (const char*)W1F, geluf, b1, 1024);

    // FFN2 + resid + LN1(blk1) -> xout0 (f32) and xnf (frags for blk1 Q-proj)
    gemm_ln<1024, true><<<MM / 64, 512, 0, stream>>>(
        (const bf16x8*)geluf, (const bf16x8*)W2F, xout0, xmid, b2,
        ln1_g + DD, ln1_b + DD, xnf);

    // ---- block 1: cross(a,b) ----
    gemm_qkv<<<dim3(MM / 128, 6), 256, 0, stream>>>(
        (const bf16x8*)xnf, (const bf16x8*)ctxfb,
        (const bf16x8*)(WQF + 65536), (const bf16x8*)(KVF + 131072), qbuf, kvbuf);

    attn_kernel<<<MM / 4, 256, 0, stream>>>(qbuf, kvbuf, coord_a, coord_b, knn_a2b,
                                            pe_w + 3 * DD, pe_b + DD, attnf);

    gemm_ln<256, false><<<MM / 64, 512, 0, stream>>>(
        (const bf16x8*)attnf, (const bf16x8*)(WOF + 65536), xmid, xout0, nullptr,
        ln2_g + DD, ln2_b + DD, xnf);

    gemm_gelu_deep<<<dim3(MM / 128, 8), 512, 0, stream>>>(
        (const char*)xnf, (const char*)(W1F + 262144), geluf, b1 + DFF_, 1024);

    // final FFN2: 64x128 tiles, grid (256,2) = 512 wgs (R14 form)
    gemm_frag64<1024, 256, true, true><<<dim3(MM / 64, 2), 256, 0, stream>>>(
        (const bf16x8*)geluf, (const bf16x8*)(W2F + 262144), (float*)d_out, xmid,
        b2 + DD);
}

// Round 10
// 313.119 us; speedup vs baseline: 1.0163x; 1.0163x over previous
//
#include <hip/hip_runtime.h>
#include <hip/hip_bf16.h>
#include <stdint.h>

#define MM 16384
#define DD 256
#define HH 4
#define KK 16
#define DFF_ 1024

typedef __attribute__((ext_vector_type(8))) short bf16x8;
typedef __attribute__((ext_vector_type(16))) float f32x16;
typedef __attribute__((ext_vector_type(2))) float f32x2;

__device__ __forceinline__ unsigned short f2bf(float f) {
    unsigned u = __builtin_bit_cast(unsigned, f);
    unsigned r = u + 0x7fffu + ((u >> 16) & 1u);
    return (unsigned short)(r >> 16);
}
__device__ __forceinline__ float bf2f(unsigned short h) {
    unsigned u = ((unsigned)h) << 16;
    return __builtin_bit_cast(float, u);
}

// ---------------------------------------------------------------------------
// Fragment layouts (bf16, 16B chunks of 8 elems):
// A-frag (row m, k):  chunk = ((m>>5)*(KD/16) + (k>>4))*64 + ((k>>3)&1)*32 + (m&31), elem = k&7
// B-frag (col n, k):  same with n.
// v_mfma_f32_32x32x16_bf16 C/D: col=lane&31, row=(reg&3)+8*(reg>>2)+4*(lane>>5)
// kv buffer: fp8 e4m3 rows of 512 B, groups of 8 B = [K4 | V4].
// NOTE (R10): gemm_ln fusion; R14: grid-starvation lever (335.7->311.8).
// NOTE (R15): 32-col wave tiles from VMEM regress; 64-col min for B-reuse.
// NOTE (R16/R17/R18): FFN1 scheduling exhausted: 4x occupancy, 2-phase
//   pipeline, full-K 128KB-in-flight prestage ALL flat (~47us). Every GEMM
//   variant lands ~180 TF; limiter is none of MFMA/VALU/L2BW/HBM/occ/depth.
// NOTE (R19/this round): producer-consumer fusion wo_ln_ffn1: Wo+resid+LN2
//   (owns 64-row strips) packs xn into LDS (bit-identical frag bytes), FFN1
//   reads A from LDS, only B (L2-hot weights) from global. -2 dispatches,
//   -16MB xnf round-trip, phase-3 VMEM/MFMA 1.5->1. Tests "A-side global
//   latency is the common wall".
// ---------------------------------------------------------------------------

// wfrag layout (shorts): WQF@0 (blk stride 65536), KVF@131072 (131072),
//   WOF@393216 (65536), W1F@524288 (262144), W2F@1048576 (262144)
__global__ __launch_bounds__(256) void prep_weights(
        const float* __restrict__ Wq, const float* __restrict__ Wk,
        const float* __restrict__ Wv, const float* __restrict__ Wo,
        const float* __restrict__ W1, const float* __restrict__ W2,
        unsigned short* __restrict__ wf) {
    int t = blockIdx.x * blockDim.x + threadIdx.x;
    const float* src; unsigned short* dst;
    int kd, lg, rem, blk, e, sect;
    if (t < 131072) { sect = 0; rem = t; blk = rem >> 16; e = rem & 65535;
        src = Wq; dst = wf + blk * 65536; kd = 256; lg = 8; }
    else if (t < 262144) { sect = 1; rem = t - 131072; blk = rem >> 16; e = rem & 65535;
        src = Wk; dst = wf + 131072 + blk * 131072; kd = 256; lg = 8; }
    else if (t < 393216) { sect = 2; rem = t - 262144; blk = rem >> 16; e = rem & 65535;
        src = Wv; dst = wf + 131072 + blk * 131072; kd = 256; lg = 8; }
    else if (t < 524288) { sect = 0; rem = t - 393216; blk = rem >> 16; e = rem & 65535;
        src = Wo; dst = wf + 393216 + blk * 65536; kd = 256; lg = 8; }
    else if (t < 1048576) { sect = 0; rem = t - 524288; blk = rem >> 18; e = rem & 262143;
        src = W1; dst = wf + 524288 + blk * 262144; kd = 256; lg = 10; }
    else if (t < 1572864) { sect = 0; rem = t - 1048576; blk = rem >> 18; e = rem & 262143;
        src = W2; dst = wf + 1048576 + blk * 262144; kd = 1024; lg = 8; }
    else return;
    int k = e >> lg;
    int n = e & ((1 << lg) - 1);
    if (sect == 1) n = (n >> 2) * 8 + (n & 3);
    else if (sect == 2) n = (n >> 2) * 8 + 4 + (n & 3);
    float v = src[(size_t)blk * kd * (1 << lg) + e];
    int off = ((n >> 5) * (kd >> 4) + (k >> 4)) * 512 + (((k >> 3) & 1) * 32 + (n & 31)) * 8 + (k & 7);
    dst[off] = f2bf(v);
}

// 3 slices in one launch: y=0: LN(xa,g,b)->outln; y=1: conv(xa)->outca; y=2: conv(xb)->outcb
__global__ __launch_bounds__(256) void ln3_to_frag(
        const float* __restrict__ xa, const float* __restrict__ g,
        const float* __restrict__ b, const float* __restrict__ xb,
        unsigned short* __restrict__ outln, unsigned short* __restrict__ outca,
        unsigned short* __restrict__ outcb) {
    int y = blockIdx.y;
    const float* x = (y == 2) ? xb : xa;
    unsigned short* out = (y == 0) ? outln : (y == 1 ? outca : outcb);
    int apply_ln = (y == 0);
    int wave = threadIdx.x >> 6, lane = threadIdx.x & 63;
    int m = blockIdx.x * 4 + wave;
    const float4 xv = reinterpret_cast<const float4*>(x + (size_t)m * DD)[lane];
    float vals[4] = {xv.x, xv.y, xv.z, xv.w};
    int k0 = lane * 4;
    if (apply_ln) {
        float s = vals[0] + vals[1] + vals[2] + vals[3];
        float sq = vals[0]*vals[0] + vals[1]*vals[1] + vals[2]*vals[2] + vals[3]*vals[3];
        for (int o = 32; o; o >>= 1) { s += __shfl_xor(s, o, 64); sq += __shfl_xor(sq, o, 64); }
        float mean = s * (1.0f / DD);
        float var = sq * (1.0f / DD) - mean * mean;
        float rs = rsqrtf(var + 1e-5f);
        #pragma unroll
        for (int c = 0; c < 4; ++c)
            vals[c] = (vals[c] - mean) * rs * g[k0 + c] + b[k0 + c];
    }
    int chunk = ((m >> 5) * (DD >> 4) + (k0 >> 4)) * 64 + ((k0 >> 3) & 1) * 32 + (m & 31);
    ushort4 o4 = make_ushort4(f2bf(vals[0]), f2bf(vals[1]), f2bf(vals[2]), f2bf(vals[3]));
    *reinterpret_cast<ushort4*>(out + (size_t)chunk * 8 + (k0 & 7)) = o4;
}

template <int KG>
__device__ __forceinline__ void compute_tile(
        const bf16x8* __restrict__ a0, const bf16x8* __restrict__ a1,
        const bf16x8* __restrict__ b0, const bf16x8* __restrict__ b1,
        f32x16 acc[2][2]) {
    #pragma unroll 4
    for (int g = 0; g < KG; ++g) {
        bf16x8 av0 = a0[g * 64];
        bf16x8 av1 = a1[g * 64];
        bf16x8 bv0 = b0[g * 64];
        bf16x8 bv1 = b1[g * 64];
        acc[0][0] = __builtin_amdgcn_mfma_f32_32x32x16_bf16(av0, bv0, acc[0][0], 0, 0, 0);
        acc[0][1] = __builtin_amdgcn_mfma_f32_32x32x16_bf16(av0, bv1, acc[0][1], 0, 0, 0);
        acc[1][0] = __builtin_amdgcn_mfma_f32_32x32x16_bf16(av1, bv0, acc[1][0], 0, 0, 0);
        acc[1][1] = __builtin_amdgcn_mfma_f32_32x32x16_bf16(av1, bv1, acc[1][1], 0, 0, 0);
    }
}

// butterfly reduce-scatter stage: N slots -> N/2 slots (xor-butterfly).
template <int O, int N>
__device__ __forceinline__ void redstage(float* a, int lane) {
    int sel = lane & O;
    #pragma unroll
    for (int u = 0; u < N / 2; ++u) {
        float lo = a[2 * u], hi = a[2 * u + 1];
        float keep = sel ? hi : lo;
        float send = sel ? lo : hi;
        a[u] = keep + __shfl_xor(send, O, 64);
    }
}

// R19: fused Wo-GEMM + resid + LN2 -> LDS xn-frags -> FFN1 + GELU -> geluf.
// wg = 64 rows, 512 thr / 8 waves. Phase 1/2 = R14 gemm_ln (2m x 4n of
// 32x64). Phase 3: FFN1 A from LDS, B (W1F) from global, 2 halves of
// N=512, wave tile 32x128 (acc 64 regs).
__global__ __launch_bounds__(512) void wo_ln_ffn1(
        const bf16x8* __restrict__ A, const bf16x8* __restrict__ Bo,
        float* __restrict__ xmid, const float* __restrict__ resid,
        const float* __restrict__ lng, const float* __restrict__ lnb,
        const bf16x8* __restrict__ B1, const float* __restrict__ b1,
        unsigned short* __restrict__ geluf) {
    constexpr int KG = 16;
    __shared__ float pstat[4][64][2];
    __shared__ float stats[64][2];
    __shared__ float tlds[8][32 * 33];
    __shared__ alignas(16) unsigned short xnlds[2][16][64][8]; // 32KB A-frags
    int wave = threadIdx.x >> 6, lane = threadIdx.x & 63;
    int wm = wave >> 2, wn = wave & 3;
    int m0 = blockIdx.x * 64;
    int mw = m0 + wm * 32;
    int n0 = wn * 64;
    const bf16x8* a0 = A + ((size_t)(mw >> 5) * KG) * 64 + lane;
    const bf16x8* b0 = Bo + ((size_t)(n0 >> 5) * KG) * 64 + lane;
    const bf16x8* b1o = b0 + (size_t)KG * 64;
    f32x16 acc[2] = {};
    #pragma unroll 4
    for (int g = 0; g < KG; ++g) {
        bf16x8 av = a0[g * 64];
        bf16x8 bv0 = b0[g * 64];
        bf16x8 bv1 = b1o[g * 64];
        acc[0] = __builtin_amdgcn_mfma_f32_32x32x16_bf16(av, bv0, acc[0], 0, 0, 0);
        acc[1] = __builtin_amdgcn_mfma_f32_32x32x16_bf16(av, bv1, acc[1], 0, 0, 0);
    }
    int col = lane & 31, rq = (lane >> 5) * 4;

    // phase 1 epilogue: v = acc + resid; write f32 xmid; stash in acc.
    #pragma unroll
    for (int j = 0; j < 2; ++j) {
        #pragma unroll
        for (int r = 0; r < 16; ++r) {
            int row = (r & 3) + 8 * (r >> 2) + rq;
            int m = mw + row;
            int n = n0 + j * 32 + col;
            float v = acc[j][r];
            v += resid[(size_t)m * DD + n];
            xmid[(size_t)m * DD + n] = v;
            acc[j][r] = v;
        }
    }

    // LN stats (R14 form).
    {
        float ps[16];
        #pragma unroll
        for (int r = 0; r < 16; ++r) ps[r] = acc[0][r] + acc[1][r];
        redstage<1, 16>(ps, lane);
        redstage<2, 8>(ps, lane);
        redstage<4, 4>(ps, lane);
        redstage<8, 2>(ps, lane);
        float sum64 = ps[0] + __shfl_xor(ps[0], 16, 64);
        float qs[16];
        #pragma unroll
        for (int r = 0; r < 16; ++r) {
            float a = acc[0][r], b = acc[1][r];
            qs[r] = a * a + b * b;
        }
        redstage<1, 16>(qs, lane);
        redstage<2, 8>(qs, lane);
        redstage<4, 4>(qs, lane);
        redstage<8, 2>(qs, lane);
        float sq64 = qs[0] + __shfl_xor(qs[0], 16, 64);
        int slot = lane & 15;
        int ROW = wm * 32 + (slot & 3) + 8 * (slot >> 2) + rq;
        if ((lane & 16) == 0)
            *reinterpret_cast<float2*>(&pstat[wn][ROW][0]) = make_float2(sum64, sq64);
    }
    __syncthreads();
    if (threadIdx.x < 64) {
        int R = threadIdx.x;
        float s = 0.0f, sq = 0.0f;
        #pragma unroll
        for (int w = 0; w < 4; ++w) {
            float2 p = *reinterpret_cast<float2*>(&pstat[w][R][0]);
            s += p.x; sq += p.y;
        }
        float mean = s * (1.0f / DD);
        float var = sq * (1.0f / DD) - mean * mean;
        float rstd = rsqrtf(var + 1e-5f);
        *reinterpret_cast<float2*>(&stats[R][0]) = make_float2(mean, rstd);
    }
    __syncthreads();

    // phase 2: normalize + transpose-pack into LDS xn-frags (bit-identical
    // bytes to the old global xnf path).
    {
        float* wlds = &tlds[wave][0];
        float mean_r[16], rstd_r[16];
        #pragma unroll
        for (int r = 0; r < 16; ++r) {
            int row = (r & 3) + 8 * (r >> 2) + rq;
            float2 st = *reinterpret_cast<float2*>(&stats[wm * 32 + row][0]);
            mean_r[r] = st.x; rstd_r[r] = st.y;
        }
        for (int j = 0; j < 2; ++j) {
            float gj = lng[n0 + j * 32 + col];
            float bj = lnb[n0 + j * 32 + col];
            #pragma unroll
            for (int r = 0; r < 16; ++r) {
                int row = (r & 3) + 8 * (r >> 2) + rq;
                float v = (acc[j][r] - mean_r[r]) * rstd_r[r] * gj + bj;
                wlds[row * 33 + col] = v;
            }
            #pragma unroll
            for (int it = 0; it < 2; ++it) {
                int task = lane + it * 64;
                int row = task >> 2, cc = task & 3;
                int m = mw + row;
                int k = n0 + j * 32 + cc * 8;
                float* p = &wlds[row * 33 + cc * 8];
                unsigned short us[8];
                #pragma unroll
                for (int e = 0; e < 8; ++e) us[e] = f2bf(p[e]);
                int lch = (k >> 4) * 64 + ((k >> 3) & 1) * 32 + (m & 31);
                reinterpret_cast<uint4*>(&xnlds[wm][0][0][0])[lch] = *reinterpret_cast<uint4*>(us);
            }
        }
    }
    __syncthreads();

    // phase 3: FFN1 (64 x 1024, K=256), A from LDS, B from global; GELU ->
    // geluf frags. Two halves of N=512; wave tile 32 x 128 (4 n-blocks).
    const bf16x8* la = (const bf16x8*)&xnlds[wm][0][0][0] + lane;
    #pragma unroll
    for (int h = 0; h < 2; ++h) {
        int nw3 = h * 512 + wn * 128;
        const bf16x8* bb = B1 + ((size_t)(nw3 >> 5) * KG) * 64 + lane;
        f32x16 acc4[4] = {};
        #pragma unroll 4
        for (int g = 0; g < KG; ++g) {
            bf16x8 av = la[g * 64];
            bf16x8 bv0 = bb[g * 64];
            bf16x8 bv1 = bb[(KG + g) * 64];
            bf16x8 bv2 = bb[(2 * KG + g) * 64];
            bf16x8 bv3 = bb[(3 * KG + g) * 64];
            acc4[0] = __builtin_amdgcn_mfma_f32_32x32x16_bf16(av, bv0, acc4[0], 0, 0, 0);
            acc4[1] = __builtin_amdgcn_mfma_f32_32x32x16_bf16(av, bv1, acc4[1], 0, 0, 0);
            acc4[2] = __builtin_amdgcn_mfma_f32_32x32x16_bf16(av, bv2, acc4[2], 0, 0, 0);
            acc4[3] = __builtin_amdgcn_mfma_f32_32x32x16_bf16(av, bv3, acc4[3], 0, 0, 0);
        }
        float* wlds = &tlds[wave][0];
        for (int j = 0; j < 4; ++j) {
            #pragma unroll
            for (int r = 0; r < 16; ++r) {
                int row = (r & 3) + 8 * (r >> 2) + rq;
                int n = nw3 + j * 32 + col;
                float v = acc4[j][r] + b1[n];
                float arg = v * (1.5957691216f + 0.0713548163f * v * v);
                v = v * __frcp_rn(1.0f + __expf(-arg));
                wlds[row * 33 + col] = v;
            }
            #pragma unroll
            for (int it = 0; it < 2; ++it) {
                int task = lane + it * 64;
                int row = task >> 2, cc = task & 3;
                int m = mw + row;
                int k = nw3 + j * 32 + cc * 8;
                float* p = &wlds[row * 33 + cc * 8];
                unsigned short us[8];
                #pragma unroll
                for (int e = 0; e < 8; ++e) us[e] = f2bf(p[e]);
                int chunk = ((m >> 5) * (DFF_ >> 4) + (k >> 4)) * 64 + ((k >> 3) & 1) * 32 + (m & 31);
                reinterpret_cast<uint4*>(geluf)[chunk] = *reinterpret_cast<uint4*>(us);
            }
        }
    }
}

// R14 form: final FFN2. 64x128 wg tile, 4 waves = 2m x 2n of 32x64 each.
template <int KD, int NOUT, bool RESID, bool BIAS>
__global__ __launch_bounds__(256) void gemm_frag64(
        const bf16x8* __restrict__ A, const bf16x8* __restrict__ B,
        float* __restrict__ outp, const float* __restrict__ resid,
        const float* __restrict__ bias) {
    constexpr int KG = KD / 16;
    int wave = threadIdx.x >> 6, lane = threadIdx.x & 63;
    int wm = wave & 1, wn = wave >> 1;
    int mw = blockIdx.x * 64 + wm * 32;
    int nw = blockIdx.y * 128 + wn * 64;
    const bf16x8* a0 = A + ((size_t)(mw >> 5) * KG) * 64 + lane;
    const bf16x8* b0 = B + ((size_t)(nw >> 5) * KG) * 64 + lane;
    const bf16x8* b1 = b0 + (size_t)KG * 64;
    f32x16 acc[2] = {};
    #pragma unroll 4
    for (int g = 0; g < KG; ++g) {
        bf16x8 av = a0[g * 64];
        bf16x8 bv0 = b0[g * 64];
        bf16x8 bv1 = b1[g * 64];
        acc[0] = __builtin_amdgcn_mfma_f32_32x32x16_bf16(av, bv0, acc[0], 0, 0, 0);
        acc[1] = __builtin_amdgcn_mfma_f32_32x32x16_bf16(av, bv1, acc[1], 0, 0, 0);
    }
    int col = lane & 31, rq = (lane >> 5) * 4;
    #pragma unroll
    for (int j = 0; j < 2; ++j) {
        #pragma unroll
        for (int r = 0; r < 16; ++r) {
            int row = (r & 3) + 8 * (r >> 2) + rq;
            int m = mw + row;
            int n = nw + j * 32 + col;
            float v = acc[j][r];
            if (BIAS) v += bias[n];
            if (RESID) v += resid[(size_t)m * NOUT + n];
            outp[(size_t)m * NOUT + n] = v;
        }
    }
}

// R14/R10 form: fused Q + KV projections, 128x128 wg tiles, direct loads.
__global__ __launch_bounds__(256) void gemm_qkv(
        const bf16x8* __restrict__ Aq, const bf16x8* __restrict__ Akv,
        const bf16x8* __restrict__ Bq, const bf16x8* __restrict__ Bkv,
        unsigned short* __restrict__ qout, unsigned char* __restrict__ kvout) {
    constexpr int KG = 16;
    int wave = threadIdx.x >> 6, lane = threadIdx.x & 63;
    int wm = wave & 1, wn = wave >> 1;
    int y = blockIdx.y;
    bool isQ = y < 2;
    const bf16x8* A = isQ ? Aq : Akv;
    const bf16x8* B = isQ ? Bq : Bkv;
    int n0 = (isQ ? y : y - 2) * 128 + wn * 64;
    int m0 = blockIdx.x * 128 + wm * 64;
    const bf16x8* a0 = A + ((size_t)(m0 >> 5) * KG) * 64 + lane;
    const bf16x8* a1 = a0 + (size_t)KG * 64;
    const bf16x8* b0 = B + ((size_t)(n0 >> 5) * KG) * 64 + lane;
    const bf16x8* b1 = b0 + (size_t)KG * 64;
    f32x16 acc[2][2] = {};
    compute_tile<KG>(a0, a1, b0, b1, acc);
    int col = lane & 31, rq = (lane >> 5) * 4;
    #pragma unroll
    for (int i = 0; i < 2; ++i)
    #pragma unroll
    for (int j = 0; j < 2; ++j)
    #pragma unroll
    for (int r = 0; r < 16; ++r) {
        int row = (r & 3) + 8 * (r >> 2) + rq;
        int m = m0 + i * 32 + row;
        int n = n0 + j * 32 + col;
        float v = acc[i][j][r];
        if (isQ) qout[(size_t)m * 256 + n] = f2bf(v);
        else kvout[(size_t)m * 512 + n] =
            (unsigned char)(__builtin_amdgcn_cvt_pk_fp8_f32(v, v, 0, false) & 0xff);
    }
}

// R14 form: Fused GEMM(+bias)+resid -> f32 C; LayerNorm rows -> bf16 A-frag.
// wg = 64 rows x 256 cols with 8 waves (512 thr), 2m x 4n of 32x64.
template <int KD, bool BIAS>
__global__ __launch_bounds__(512) void gemm_ln(
        const bf16x8* __restrict__ A, const bf16x8* __restrict__ B,
        float* __restrict__ out_f32, const float* __restrict__ resid,
        const float* __restrict__ bias,
        const float* __restrict__ lng, const float* __restrict__ lnb,
        unsigned short* __restrict__ out_frag) {
    constexpr int KG = KD / 16;
    __shared__ float pstat[4][64][2];   // [wn][block row][sum,sumsq]
    __shared__ float stats[64][2];      // [block row][mean, rstd]
    __shared__ float tlds[8][32 * 33];  // per-wave transpose pads
    int wave = threadIdx.x >> 6, lane = threadIdx.x & 63;
    int wm = wave >> 2, wn = wave & 3;
    int m0 = blockIdx.x * 64;
    int mw = m0 + wm * 32;
    int n0 = wn * 64;
    const bf16x8* a0 = A + ((size_t)(mw >> 5) * KG) * 64 + lane;
    const bf16x8* b0 = B + ((size_t)(n0 >> 5) * KG) * 64 + lane;
    const bf16x8* b1 = b0 + (size_t)KG * 64;
    f32x16 acc[2] = {};
    #pragma unroll 4
    for (int g = 0; g < KG; ++g) {
        bf16x8 av = a0[g * 64];
        bf16x8 bv0 = b0[g * 64];
        bf16x8 bv1 = b1[g * 64];
        acc[0] = __builtin_amdgcn_mfma_f32_32x32x16_bf16(av, bv0, acc[0], 0, 0, 0);
        acc[1] = __builtin_amdgcn_mfma_f32_32x32x16_bf16(av, bv1, acc[1], 0, 0, 0);
    }
    int col = lane & 31, rq = (lane >> 5) * 4;

    // epilogue pass 1: v = acc (+bias) + resid; write f32; stash v in acc.
    #pragma unroll
    for (int j = 0; j < 2; ++j) {
        #pragma unroll
        for (int r = 0; r < 16; ++r) {
            int row = (r & 3) + 8 * (r >> 2) + rq;
            int m = mw + row;
            int n = n0 + j * 32 + col;
            float v = acc[j][r];
            if (BIAS) v += bias[n];
            v += resid[(size_t)m * DD + n];
            out_f32[(size_t)m * DD + n] = v;
            acc[j][r] = v;
        }
    }

    // per-wave row sums over this wave's 64 cols (16 slots, 4 stages + xor16).
    {
        float ps[16];
        #pragma unroll
        for (int r = 0; r < 16; ++r)
            ps[r] = acc[0][r] + acc[1][r];
        redstage<1, 16>(ps, lane);
        redstage<2, 8>(ps, lane);
        redstage<4, 4>(ps, lane);
        redstage<8, 2>(ps, lane);
        float sum64 = ps[0] + __shfl_xor(ps[0], 16, 64);
        float qs[16];
        #pragma unroll
        for (int r = 0; r < 16; ++r) {
            float a = acc[0][r], b = acc[1][r];
            qs[r] = a * a + b * b;
        }
        redstage<1, 16>(qs, lane);
        redstage<2, 8>(qs, lane);
        redstage<4, 4>(qs, lane);
        redstage<8, 2>(qs, lane);
        float sq64 = qs[0] + __shfl_xor(qs[0], 16, 64);
        int slot = lane & 15;
        int ROW = wm * 32 + (slot & 3) + 8 * (slot >> 2) + rq;
        if ((lane & 16) == 0)
            *reinterpret_cast<float2*>(&pstat[wn][ROW][0]) = make_float2(sum64, sq64);
    }
    __syncthreads();
    if (threadIdx.x < 64) {
        int R = threadIdx.x;
        float s = 0.0f, sq = 0.0f;
        #pragma unroll
        for (int w = 0; w < 4; ++w) {
            float2 p = *reinterpret_cast<float2*>(&pstat[w][R][0]);
            s += p.x; sq += p.y;
        }
        float mean = s * (1.0f / DD);
        float var = sq * (1.0f / DD) - mean * mean;
        float rstd = rsqrtf(var + 1e-5f);
        *reinterpret_cast<float2*>(&stats[R][0]) = make_float2(mean, rstd);
    }
    __syncthreads();

    // normalize + transpose-pack to frags (pad-33 wave-private tiles).
    float* wlds = &tlds[wave][0];
    float mean_r[16], rstd_r[16];
    #pragma unroll
    for (int r = 0; r < 16; ++r) {
        int row = (r & 3) + 8 * (r >> 2) + rq;
        float2 st = *reinterpret_cast<float2*>(&stats[wm * 32 + row][0]);
        mean_r[r] = st.x; rstd_r[r] = st.y;
    }
    for (int j = 0; j < 2; ++j) {
        float gj = lng[n0 + j * 32 + col];
        float bj = lnb[n0 + j * 32 + col];
        #pragma unroll
        for (int r = 0; r < 16; ++r) {
            int row = (r & 3) + 8 * (r >> 2) + rq;
            float v = (acc[j][r] - mean_r[r]) * rstd_r[r] * gj + bj;
            wlds[row * 33 + col] = v;
        }
        #pragma unroll
        for (int it = 0; it < 2; ++it) {
            int task = lane + it * 64;
            int row = task >> 2, cc = task & 3;
            int m = mw + row;
            int k = n0 + j * 32 + cc * 8;
            float* p = &wlds[row * 33 + cc * 8];
            unsigned short us[8];
            #pragma unroll
            for (int e = 0; e < 8; ++e) us[e] = f2bf(p[e]);
            int chunk = ((m >> 5) * (DD >> 4) + (k >> 4)) * 64 + ((k >> 3) & 1) * 32 + (m & 31);
            *reinterpret_cast<uint4*>(out_frag + (size_t)chunk * 8) = *reinterpret_cast<uint4*>(us);
        }
    }
}

// One wave per point. lane = h*16+s; dims d0 = h*64+s*4.
// Distributed scores; pe handled algebraically. kv rows: 512 B fp8.
// R12: score reduction via butterfly reduce-scatter (15 shfl vs 64).
__global__ __launch_bounds__(256) void attn_kernel(
        const unsigned short* __restrict__ q, const unsigned char* __restrict__ kv,
        const float* __restrict__ coord, const float* __restrict__ ctx_coord,
        const int* __restrict__ knn,
        const float* __restrict__ pe_w, const float* __restrict__ pe_b,
        unsigned short* __restrict__ out_frag) {
    int wave = threadIdx.x >> 6, lane = threadIdx.x & 63;
    int m = blockIdx.x * 4 + wave;
    int s = lane & 15;
    int d0 = (lane >> 4) * 64 + s * 4;

    ushort4 qv4 = *reinterpret_cast<const ushort4*>(q + (size_t)m * DD + d0);
    float qx = bf2f(qv4.x), qy = bf2f(qv4.y), qz = bf2f(qv4.z), qw = bf2f(qv4.w);
    float4 pw0 = *reinterpret_cast<const float4*>(pe_w + d0);
    float4 pw1 = *reinterpret_cast<const float4*>(pe_w + DD + d0);
    float4 pw2 = *reinterpret_cast<const float4*>(pe_w + 2 * DD + d0);
    float4 pbv = *reinterpret_cast<const float4*>(pe_b + d0);

    float cx = coord[m * 3], cy = coord[m * 3 + 1], cz = coord[m * 3 + 2];
    int myidx = knn[(size_t)m * KK + s];
    int icm = myidx < 0 ? 0 : myidx;
    float rx = cx - ctx_coord[icm * 3];
    float ry = cy - ctx_coord[icm * 3 + 1];
    float rz = cz - ctx_coord[icm * 3 + 2];

    float t0 = qx * pw0.x + qy * pw0.y + qz * pw0.z + qw * pw0.w;
    float t1 = qx * pw1.x + qy * pw1.y + qz * pw1.z + qw * pw1.w;
    float t2 = qx * pw2.x + qy * pw2.y + qz * pw2.z + qw * pw2.w;
    float t3 = qx * pbv.x + qy * pbv.y + qz * pbv.z + qw * pbv.w;
    #pragma unroll
    for (int o = 1; o < 16; o <<= 1) {
        t0 += __shfl_xor(t0, o, 64);
        t1 += __shfl_xor(t1, o, 64);
        t2 += __shfl_xor(t2, o, 64);
        t3 += __shfl_xor(t3, o, 64);
    }

    // per-lane partials for all 16 scores, then one butterfly reduce-scatter
    float P[KK];
    unsigned vpk[KK];
    #pragma unroll
    for (int j = 0; j < KK; ++j) {
        int ij = __shfl(myidx, j, 64);
        int ic = ij < 0 ? 0 : ij;
        uint2 kvv = *reinterpret_cast<const uint2*>(kv + (size_t)ic * 512 + (d0 >> 2) * 8);
        vpk[j] = kvv.y;
        f32x2 k01 = __builtin_amdgcn_cvt_pk_f32_fp8(kvv.x, false);
        f32x2 k23 = __builtin_amdgcn_cvt_pk_f32_fp8(kvv.x, true);
        P[j] = qx * k01.x + qy * k01.y + qz * k23.x + qw * k23.y;
    }
    redstage<1, 16>(P, lane);
    redstage<2, 8>(P, lane);
    redstage<4, 4>(P, lane);
    redstage<8, 2>(P, lane);
    float corr = rx * t0 + ry * t1 + rz * t2 + t3;
    float sc_own = (myidx >= 0) ? (P[0] + corr) * 0.125f : -1e9f;

    float mx = sc_own;
    mx = fmaxf(mx, __shfl_xor(mx, 1, 64));
    mx = fmaxf(mx, __shfl_xor(mx, 2, 64));
    mx = fmaxf(mx, __shfl_xor(mx, 4, 64));
    mx = fmaxf(mx, __shfl_xor(mx, 8, 64));
    float e = __expf(sc_own - mx);
    float sum = e;
    sum += __shfl_xor(sum, 1, 64);
    sum += __shfl_xor(sum, 2, 64);
    sum += __shfl_xor(sum, 4, 64);
    sum += __shfl_xor(sum, 8, 64);
    float w_own = e * __frcp_rn(sum);

    float wrx = w_own * rx, wry = w_own * ry, wrz = w_own * rz;
    #pragma unroll
    for (int o = 1; o < 16; o <<= 1) {
        wrx += __shfl_xor(wrx, o, 64);
        wry += __shfl_xor(wry, o, 64);
        wrz += __shfl_xor(wrz, o, 64);
    }

    int gbase = lane & 48;
    float ax = 0.f, ay = 0.f, az = 0.f, aw = 0.f;
    #pragma unroll
    for (int j = 0; j < KK; ++j) {
        float wj = __shfl(w_own, gbase + j, 64);
        f32x2 v01 = __builtin_amdgcn_cvt_pk_f32_fp8(vpk[j], false);
        f32x2 v23 = __builtin_amdgcn_cvt_pk_f32_fp8(vpk[j], true);
        ax += wj * v01.x;
        ay += wj * v01.y;
        az += wj * v23.x;
        aw += wj * v23.y;
    }
    ax += wrx * pw0.x + wry * pw1.x + wrz * pw2.x + pbv.x;
    ay += wrx * pw0.y + wry * pw1.y + wrz * pw2.y + pbv.y;
    az += wrx * pw0.z + wry * pw1.z + wrz * pw2.z + pbv.z;
    aw += wrx * pw0.w + wry * pw1.w + wrz * pw2.w + pbv.w;

    ushort4 o4 = make_ushort4(f2bf(ax), f2bf(ay), f2bf(az), f2bf(aw));
    int chunk = ((m >> 5) * (DD >> 4) + (d0 >> 4)) * 64 + ((d0 >> 3) & 1) * 32 + (m & 31);
    *reinterpret_cast<ushort4*>(out_frag + (size_t)chunk * 8 + (d0 & 7)) = o4;
}

extern "C" void kernel_launch(void* const* d_in, const int* in_sizes, int n_in,
                              void* d_out, int out_size, void* d_ws, size_t ws_size,
                              hipStream_t stream) {
    const float* feat_a = (const float*)d_in[0];
    const float* coord_a = (const float*)d_in[1];
    const float* feat_b = (const float*)d_in[2];
    const float* coord_b = (const float*)d_in[3];
    const float* Wq = (const float*)d_in[4];
    const float* Wk = (const float*)d_in[5];
    const float* Wv = (const float*)d_in[6];
    const float* Wo = (const float*)d_in[7];
    const float* ln1_g = (const float*)d_in[8];
    const float* ln1_b = (const float*)d_in[9];
    const float* pe_w = (const float*)d_in[10];
    const float* pe_b = (const float*)d_in[11];
    const float* W1 = (const float*)d_in[12];
    const float* b1 = (const float*)d_in[13];
    const float* W2 = (const float*)d_in[14];
    const float* b2 = (const float*)d_in[15];
    const float* ln2_g = (const float*)d_in[16];
    const float* ln2_b = (const float*)d_in[17];
    const int* knn_a2a = (const int*)d_in[18];
    const int* knn_a2b = (const int*)d_in[19];

    char* ws = (char*)d_ws;
    unsigned short* wfrag = (unsigned short*)ws;                  // 3 MB (4 MB region)
    float* xmid = (float*)(ws + (4ull << 20));                    // 16 MB
    float* xout0 = (float*)(ws + (20ull << 20));                  // 16 MB
    unsigned short* qbuf = (unsigned short*)(ws + (36ull << 20)); // 8 MB
    unsigned char* kvbuf = (unsigned char*)(ws + (52ull << 20));  // 8 MB (fp8)
    unsigned short* xnf = (unsigned short*)(ws + (68ull << 20));  // 8 MB
    unsigned short* ctxfa = (unsigned short*)(ws + (76ull << 20));// 8 MB
    unsigned short* attnf = (unsigned short*)(ws + (84ull << 20));// 8 MB
    unsigned short* ctxfb = (unsigned short*)(ws + (92ull << 20));// 8 MB -> 100 MB
    unsigned short* geluf = (unsigned short*)(ws + (36ull << 20));// 32 MB, overlays q/kv (dead by FFN)

    const unsigned short* WQF = wfrag;
    const unsigned short* KVF = wfrag + 131072;
    const unsigned short* WOF = wfrag + 393216;
    const unsigned short* W1F = wfrag + 524288;
    const unsigned short* W2F = wfrag + 1048576;

    prep_weights<<<(1572864 + 255) / 256, 256, 0, stream>>>(Wq, Wk, Wv, Wo, W1, W2, wfrag);

    // one launch: xnf = LN1(feat_a); ctxfa = conv(feat_a); ctxfb = conv(feat_b)
    ln3_to_frag<<<dim3(MM / 4, 3), 256, 0, stream>>>(feat_a, ln1_g, ln1_b, feat_b,
                                                     xnf, ctxfa, ctxfb);

    // ---- block 0: self(a) ----
    gemm_qkv<<<dim3(MM / 128, 6), 256, 0, stream>>>(
        (const bf16x8*)xnf, (const bf16x8*)ctxfa,
        (const bf16x8*)WQF, (const bf16x8*)KVF, qbuf, kvbuf);

    attn_kernel<<<MM / 4, 256, 0, stream>>>(qbuf, kvbuf, coord_a, coord_a, knn_a2a,
                                            pe_w, pe_b, attnf);

    // Wo + resid + LN2 + FFN1 + GELU fused (xn stays in LDS)
    wo_ln_ffn1<<<MM / 64, 512, 0, stream>>>(
        (const bf16x8*)attnf, (const bf16x8*)WOF, xmid, feat_a,
        ln2_g, ln2_b, (const bf16x8*)W1F, b1, geluf);

    // FFN2 + resid + LN1(blk1) -> xout0 (f32) and xnf (frags for blk1 Q-proj)
    gemm_ln<1024, true><<<MM / 64, 512, 0, stream>>>(
        (const bf16x8*)geluf, (const bf16x8*)W2F, xout0, xmid, b2,
        ln1_g + DD, ln1_b + DD, xnf);

    // ---- block 1: cross(a,b) ----
    gemm_qkv<<<dim3(MM / 128, 6), 256, 0, stream>>>(
        (const bf16x8*)xnf, (const bf16x8*)ctxfb,
        (const bf16x8*)(WQF + 65536), (const bf16x8*)(KVF + 131072), qbuf, kvbuf);

    attn_kernel<<<MM / 4, 256, 0, stream>>>(qbuf, kvbuf, coord_a, coord_b, knn_a2b,
                                            pe_w + 3 * DD, pe_b + DD, attnf);

    wo_ln_ffn1<<<MM / 64, 512, 0, stream>>>(
        (const bf16x8*)attnf, (const bf16x8*)(WOF + 65536), xmid, xout0,
        ln2_g + DD, ln2_b + DD, (const bf16x8*)(W1F + 262144), b1 + DFF_, geluf);

    // final FFN2: 64x128 tiles, grid (256,2) = 512 wgs (R14 form)
    gemm_frag64<1024, 256, true, true><<<dim3(MM / 64, 2), 256, 0, stream>>>(
        (const bf16x8*)geluf, (const bf16x8*)(W2F + 262144), (float*)d_out, xmid,
        b2 + DD);
}

// Round 11
// 311.332 us; speedup vs baseline: 1.0221x; 1.0057x over previous
//
#include <hip/hip_runtime.h>
#include <hip/hip_bf16.h>
#include <stdint.h>

#define MM 16384
#define DD 256
#define HH 4
#define KK 16
#define DFF_ 1024

typedef __attribute__((ext_vector_type(8))) short bf16x8;
typedef __attribute__((ext_vector_type(16))) float f32x16;
typedef __attribute__((ext_vector_type(2))) float f32x2;

__device__ __forceinline__ unsigned short f2bf(float f) {
    unsigned u = __builtin_bit_cast(unsigned, f);
    unsigned r = u + 0x7fffu + ((u >> 16) & 1u);
    return (unsigned short)(r >> 16);
}
__device__ __forceinline__ float bf2f(unsigned short h) {
    unsigned u = ((unsigned)h) << 16;
    return __builtin_bit_cast(float, u);
}

// ---------------------------------------------------------------------------
// Fragment layouts (bf16, 16B chunks of 8 elems):
// A-frag (row m, k):  chunk = ((m>>5)*(KD/16) + (k>>4))*64 + ((k>>3)&1)*32 + (m&31), elem = k&7
// B-frag (col n, k):  same with n.
// v_mfma_f32_32x32x16_bf16 C/D: col=lane&31, row=(reg&3)+8*(reg>>2)+4*(lane>>5)
// kv buffer: fp8 e4m3 rows of 512 B, groups of 8 B = [K4 | V4].
// NOTE (R10): gemm_ln fusion; R14: grid-starvation lever (335.7->311.8).
// NOTE (R15): 32-col wave tiles from VMEM regress; 64-col min for B-reuse.
// NOTE (R16/R17/R18/R19): FFN1 wall at ~180 TF survives: 4x occupancy,
//   2-phase pipeline, 128KB-in-flight prestage, A-from-LDS fusion -- all
//   flat. Surviving model: HW caps outstanding cache lines per CU (~6KB);
//   throughput = cap/latency. Only lever left: reduce LATENCY (L3->L2).
// NOTE (R20/this round): XCD-aware bijective block swizzle on
//   gemm_gelu/gemm_qkv/gemm_frag64 so each XCD owns a contiguous M-band
//   (A-panel <= ~1-4MB becomes L2-resident, reused by all N-columns on
//   that XCD). Index remap only -- zero numeric change. gemm_ln skipped
//   (no cross-block A reuse). Structure = R16 best-known set.
// ---------------------------------------------------------------------------

// wfrag layout (shorts): WQF@0 (blk stride 65536), KVF@131072 (131072),
//   WOF@393216 (65536), W1F@524288 (262144), W2F@1048576 (262144)
__global__ __launch_bounds__(256) void prep_weights(
        const float* __restrict__ Wq, const float* __restrict__ Wk,
        const float* __restrict__ Wv, const float* __restrict__ Wo,
        const float* __restrict__ W1, const float* __restrict__ W2,
        unsigned short* __restrict__ wf) {
    int t = blockIdx.x * blockDim.x + threadIdx.x;
    const float* src; unsigned short* dst;
    int kd, lg, rem, blk, e, sect;
    if (t < 131072) { sect = 0; rem = t; blk = rem >> 16; e = rem & 65535;
        src = Wq; dst = wf + blk * 65536; kd = 256; lg = 8; }
    else if (t < 262144) { sect = 1; rem = t - 131072; blk = rem >> 16; e = rem & 65535;
        src = Wk; dst = wf + 131072 + blk * 131072; kd = 256; lg = 8; }
    else if (t < 393216) { sect = 2; rem = t - 262144; blk = rem >> 16; e = rem & 65535;
        src = Wv; dst = wf + 131072 + blk * 131072; kd = 256; lg = 8; }
    else if (t < 524288) { sect = 0; rem = t - 393216; blk = rem >> 16; e = rem & 65535;
        src = Wo; dst = wf + 393216 + blk * 65536; kd = 256; lg = 8; }
    else if (t < 1048576) { sect = 0; rem = t - 524288; blk = rem >> 18; e = rem & 262143;
        src = W1; dst = wf + 524288 + blk * 262144; kd = 256; lg = 10; }
    else if (t < 1572864) { sect = 0; rem = t - 1048576; blk = rem >> 18; e = rem & 262143;
        src = W2; dst = wf + 1048576 + blk * 262144; kd = 1024; lg = 8; }
    else return;
    int k = e >> lg;
    int n = e & ((1 << lg) - 1);
    if (sect == 1) n = (n >> 2) * 8 + (n & 3);
    else if (sect == 2) n = (n >> 2) * 8 + 4 + (n & 3);
    float v = src[(size_t)blk * kd * (1 << lg) + e];
    int off = ((n >> 5) * (kd >> 4) + (k >> 4)) * 512 + (((k >> 3) & 1) * 32 + (n & 31)) * 8 + (k & 7);
    dst[off] = f2bf(v);
}

// 3 slices in one launch: y=0: LN(xa,g,b)->outln; y=1: conv(xa)->outca; y=2: conv(xb)->outcb
__global__ __launch_bounds__(256) void ln3_to_frag(
        const float* __restrict__ xa, const float* __restrict__ g,
        const float* __restrict__ b, const float* __restrict__ xb,
        unsigned short* __restrict__ outln, unsigned short* __restrict__ outca,
        unsigned short* __restrict__ outcb) {
    int y = blockIdx.y;
    const float* x = (y == 2) ? xb : xa;
    unsigned short* out = (y == 0) ? outln : (y == 1 ? outca : outcb);
    int apply_ln = (y == 0);
    int wave = threadIdx.x >> 6, lane = threadIdx.x & 63;
    int m = blockIdx.x * 4 + wave;
    const float4 xv = reinterpret_cast<const float4*>(x + (size_t)m * DD)[lane];
    float vals[4] = {xv.x, xv.y, xv.z, xv.w};
    int k0 = lane * 4;
    if (apply_ln) {
        float s = vals[0] + vals[1] + vals[2] + vals[3];
        float sq = vals[0]*vals[0] + vals[1]*vals[1] + vals[2]*vals[2] + vals[3]*vals[3];
        for (int o = 32; o; o >>= 1) { s += __shfl_xor(s, o, 64); sq += __shfl_xor(sq, o, 64); }
        float mean = s * (1.0f / DD);
        float var = sq * (1.0f / DD) - mean * mean;
        float rs = rsqrtf(var + 1e-5f);
        #pragma unroll
        for (int c = 0; c < 4; ++c)
            vals[c] = (vals[c] - mean) * rs * g[k0 + c] + b[k0 + c];
    }
    int chunk = ((m >> 5) * (DD >> 4) + (k0 >> 4)) * 64 + ((k0 >> 3) & 1) * 32 + (m & 31);
    ushort4 o4 = make_ushort4(f2bf(vals[0]), f2bf(vals[1]), f2bf(vals[2]), f2bf(vals[3]));
    *reinterpret_cast<ushort4*>(out + (size_t)chunk * 8 + (k0 & 7)) = o4;
}

template <int KG>
__device__ __forceinline__ void compute_tile(
        const bf16x8* __restrict__ a0, const bf16x8* __restrict__ a1,
        const bf16x8* __restrict__ b0, const bf16x8* __restrict__ b1,
        f32x16 acc[2][2]) {
    #pragma unroll 4
    for (int g = 0; g < KG; ++g) {
        bf16x8 av0 = a0[g * 64];
        bf16x8 av1 = a1[g * 64];
        bf16x8 bv0 = b0[g * 64];
        bf16x8 bv1 = b1[g * 64];
        acc[0][0] = __builtin_amdgcn_mfma_f32_32x32x16_bf16(av0, bv0, acc[0][0], 0, 0, 0);
        acc[0][1] = __builtin_amdgcn_mfma_f32_32x32x16_bf16(av0, bv1, acc[0][1], 0, 0, 0);
        acc[1][0] = __builtin_amdgcn_mfma_f32_32x32x16_bf16(av1, bv0, acc[1][0], 0, 0, 0);
        acc[1][1] = __builtin_amdgcn_mfma_f32_32x32x16_bf16(av1, bv1, acc[1][1], 0, 0, 0);
    }
}

// R20: FFN1 + GELU with XCD swizzle. wg = 64x128 (4 waves 2m x 2n of 32x64),
// 1D grid 2048: xcd=id&7, slot=id>>3; bx=32*xcd+(slot&31), by=slot>>5.
// Each XCD's A-band = 32 x-tiles x 32KB = 1MB (L2-resident, reused by 8 y).
__global__ __launch_bounds__(256) void gemm_gelu(
        const bf16x8* __restrict__ A, const bf16x8* __restrict__ B,
        unsigned short* __restrict__ outp, const float* __restrict__ bias,
        int out_kd) {
    constexpr int KG = 16;
    __shared__ float lds[4 * 1056];
    int wave = threadIdx.x >> 6, lane = threadIdx.x & 63;
    int wm = wave & 1, wn = wave >> 1;
    int id = blockIdx.x;
    int xcd = id & 7, slot = id >> 3;
    int bx = 32 * xcd + (slot & 31);
    int by = slot >> 5;
    int mw = bx * 64 + wm * 32;
    int nw = by * 128 + wn * 64;
    const bf16x8* a0 = A + ((size_t)(mw >> 5) * KG) * 64 + lane;
    const bf16x8* b0 = B + ((size_t)(nw >> 5) * KG) * 64 + lane;
    const bf16x8* b1 = b0 + (size_t)KG * 64;
    f32x16 acc[2] = {};
    #pragma unroll 4
    for (int g = 0; g < KG; ++g) {
        bf16x8 av = a0[g * 64];
        bf16x8 bv0 = b0[g * 64];
        bf16x8 bv1 = b1[g * 64];
        acc[0] = __builtin_amdgcn_mfma_f32_32x32x16_bf16(av, bv0, acc[0], 0, 0, 0);
        acc[1] = __builtin_amdgcn_mfma_f32_32x32x16_bf16(av, bv1, acc[1], 0, 0, 0);
    }
    int col = lane & 31, rq = (lane >> 5) * 4;
    float* wlds = &lds[wave * 1056];
    for (int j = 0; j < 2; ++j) {
        #pragma unroll
        for (int r = 0; r < 16; ++r) {
            int row = (r & 3) + 8 * (r >> 2) + rq;
            int n = nw + j * 32 + col;
            float v = acc[j][r] + bias[n];
            float arg = v * (1.5957691216f + 0.0713548163f * v * v);
            v = v * __frcp_rn(1.0f + __expf(-arg));
            wlds[row * 33 + col] = v;
        }
        #pragma unroll
        for (int it = 0; it < 2; ++it) {
            int task = lane + it * 64;
            int row = task >> 2, cc = task & 3;
            int m = mw + row;
            int k = nw + j * 32 + cc * 8;
            float* p = &wlds[row * 33 + cc * 8];
            unsigned short us[8];
            #pragma unroll
            for (int e = 0; e < 8; ++e) us[e] = f2bf(p[e]);
            int chunk = ((m >> 5) * (out_kd >> 4) + (k >> 4)) * 64 + ((k >> 3) & 1) * 32 + (m & 31);
            reinterpret_cast<uint4*>(outp)[chunk] = *reinterpret_cast<uint4*>(us);
        }
    }
}

// R20: final FFN2 with XCD swizzle. 64x128 wg tile, 4 waves = 2m x 2n of
// 32x64. 1D grid 512: xcd=id&7, slot=id>>3; bx=32*xcd+(slot>>1), by=slot&1
// (the 2 y-blocks sharing an A strip run adjacently on the same XCD).
template <int KD, int NOUT, bool RESID, bool BIAS>
__global__ __launch_bounds__(256) void gemm_frag64(
        const bf16x8* __restrict__ A, const bf16x8* __restrict__ B,
        float* __restrict__ outp, const float* __restrict__ resid,
        const float* __restrict__ bias) {
    constexpr int KG = KD / 16;
    int wave = threadIdx.x >> 6, lane = threadIdx.x & 63;
    int wm = wave & 1, wn = wave >> 1;
    int id = blockIdx.x;
    int xcd = id & 7, slot = id >> 3;
    int bx = 32 * xcd + (slot >> 1);
    int by = slot & 1;
    int mw = bx * 64 + wm * 32;
    int nw = by * 128 + wn * 64;
    const bf16x8* a0 = A + ((size_t)(mw >> 5) * KG) * 64 + lane;
    const bf16x8* b0 = B + ((size_t)(nw >> 5) * KG) * 64 + lane;
    const bf16x8* b1 = b0 + (size_t)KG * 64;
    f32x16 acc[2] = {};
    #pragma unroll 4
    for (int g = 0; g < KG; ++g) {
        bf16x8 av = a0[g * 64];
        bf16x8 bv0 = b0[g * 64];
        bf16x8 bv1 = b1[g * 64];
        acc[0] = __builtin_amdgcn_mfma_f32_32x32x16_bf16(av, bv0, acc[0], 0, 0, 0);
        acc[1] = __builtin_amdgcn_mfma_f32_32x32x16_bf16(av, bv1, acc[1], 0, 0, 0);
    }
    int col = lane & 31, rq = (lane >> 5) * 4;
    #pragma unroll
    for (int j = 0; j < 2; ++j) {
        #pragma unroll
        for (int r = 0; r < 16; ++r) {
            int row = (r & 3) + 8 * (r >> 2) + rq;
            int m = mw + row;
            int n = nw + j * 32 + col;
            float v = acc[j][r];
            if (BIAS) v += bias[n];
            if (RESID) v += resid[(size_t)m * NOUT + n];
            outp[(size_t)m * NOUT + n] = v;
        }
    }
}

// R20: fused Q + KV projections with XCD swizzle. 128x128 wg tiles, direct
// loads. 1D grid 768: xcd=id&7, slot=id>>3 (0..95); bx=16*xcd+(slot&15),
// y=slot>>4 (0..5). A-band per XCD = 16 x-tiles x 64KB = 1MB.
__global__ __launch_bounds__(256) void gemm_qkv(
        const bf16x8* __restrict__ Aq, const bf16x8* __restrict__ Akv,
        const bf16x8* __restrict__ Bq, const bf16x8* __restrict__ Bkv,
        unsigned short* __restrict__ qout, unsigned char* __restrict__ kvout) {
    constexpr int KG = 16;
    int wave = threadIdx.x >> 6, lane = threadIdx.x & 63;
    int wm = wave & 1, wn = wave >> 1;
    int id = blockIdx.x;
    int xcd = id & 7, slot = id >> 3;
    int bx = 16 * xcd + (slot & 15);
    int y = slot >> 4;
    bool isQ = y < 2;
    const bf16x8* A = isQ ? Aq : Akv;
    const bf16x8* B = isQ ? Bq : Bkv;
    int n0 = (isQ ? y : y - 2) * 128 + wn * 64;
    int m0 = bx * 128 + wm * 64;
    const bf16x8* a0 = A + ((size_t)(m0 >> 5) * KG) * 64 + lane;
    const bf16x8* a1 = a0 + (size_t)KG * 64;
    const bf16x8* b0 = B + ((size_t)(n0 >> 5) * KG) * 64 + lane;
    const bf16x8* b1 = b0 + (size_t)KG * 64;
    f32x16 acc[2][2] = {};
    compute_tile<KG>(a0, a1, b0, b1, acc);
    int col = lane & 31, rq = (lane >> 5) * 4;
    #pragma unroll
    for (int i = 0; i < 2; ++i)
    #pragma unroll
    for (int j = 0; j < 2; ++j)
    #pragma unroll
    for (int r = 0; r < 16; ++r) {
        int row = (r & 3) + 8 * (r >> 2) + rq;
        int m = m0 + i * 32 + row;
        int n = n0 + j * 32 + col;
        float v = acc[i][j][r];
        if (isQ) qout[(size_t)m * 256 + n] = f2bf(v);
        else kvout[(size_t)m * 512 + n] =
            (unsigned char)(__builtin_amdgcn_cvt_pk_fp8_f32(v, v, 0, false) & 0xff);
    }
}

// butterfly reduce-scatter stage: N slots -> N/2 slots (xor-butterfly).
template <int O, int N>
__device__ __forceinline__ void redstage(float* a, int lane) {
    int sel = lane & O;
    #pragma unroll
    for (int u = 0; u < N / 2; ++u) {
        float lo = a[2 * u], hi = a[2 * u + 1];
        float keep = sel ? hi : lo;
        float send = sel ? lo : hi;
        a[u] = keep + __shfl_xor(send, O, 64);
    }
}

// R14 form: Fused GEMM(+bias)+resid -> f32 C; LayerNorm rows -> bf16 A-frag.
// wg = 64 rows x 256 cols with 8 waves (512 thr), 2m x 4n of 32x64.
template <int KD, bool BIAS>
__global__ __launch_bounds__(512) void gemm_ln(
        const bf16x8* __restrict__ A, const bf16x8* __restrict__ B,
        float* __restrict__ out_f32, const float* __restrict__ resid,
        const float* __restrict__ bias,
        const float* __restrict__ lng, const float* __restrict__ lnb,
        unsigned short* __restrict__ out_frag) {
    constexpr int KG = KD / 16;
    __shared__ float pstat[4][64][2];   // [wn][block row][sum,sumsq]
    __shared__ float stats[64][2];      // [block row][mean, rstd]
    __shared__ float tlds[8][32 * 33];  // per-wave transpose pads
    int wave = threadIdx.x >> 6, lane = threadIdx.x & 63;
    int wm = wave >> 2, wn = wave & 3;
    int m0 = blockIdx.x * 64;
    int mw = m0 + wm * 32;
    int n0 = wn * 64;
    const bf16x8* a0 = A + ((size_t)(mw >> 5) * KG) * 64 + lane;
    const bf16x8* b0 = B + ((size_t)(n0 >> 5) * KG) * 64 + lane;
    const bf16x8* b1 = b0 + (size_t)KG * 64;
    f32x16 acc[2] = {};
    #pragma unroll 4
    for (int g = 0; g < KG; ++g) {
        bf16x8 av = a0[g * 64];
        bf16x8 bv0 = b0[g * 64];
        bf16x8 bv1 = b1[g * 64];
        acc[0] = __builtin_amdgcn_mfma_f32_32x32x16_bf16(av, bv0, acc[0], 0, 0, 0);
        acc[1] = __builtin_amdgcn_mfma_f32_32x32x16_bf16(av, bv1, acc[1], 0, 0, 0);
    }
    int col = lane & 31, rq = (lane >> 5) * 4;

    // epilogue pass 1: v = acc (+bias) + resid; write f32; stash v in acc.
    #pragma unroll
    for (int j = 0; j < 2; ++j) {
        #pragma unroll
        for (int r = 0; r < 16; ++r) {
            int row = (r & 3) + 8 * (r >> 2) + rq;
            int m = mw + row;
            int n = n0 + j * 32 + col;
            float v = acc[j][r];
            if (BIAS) v += bias[n];
            v += resid[(size_t)m * DD + n];
            out_f32[(size_t)m * DD + n] = v;
            acc[j][r] = v;
        }
    }

    // per-wave row sums over this wave's 64 cols (16 slots, 4 stages + xor16).
    {
        float ps[16];
        #pragma unroll
        for (int r = 0; r < 16; ++r)
            ps[r] = acc[0][r] + acc[1][r];
        redstage<1, 16>(ps, lane);
        redstage<2, 8>(ps, lane);
        redstage<4, 4>(ps, lane);
        redstage<8, 2>(ps, lane);
        float sum64 = ps[0] + __shfl_xor(ps[0], 16, 64);
        float qs[16];
        #pragma unroll
        for (int r = 0; r < 16; ++r) {
            float a = acc[0][r], b = acc[1][r];
            qs[r] = a * a + b * b;
        }
        redstage<1, 16>(qs, lane);
        redstage<2, 8>(qs, lane);
        redstage<4, 4>(qs, lane);
        redstage<8, 2>(qs, lane);
        float sq64 = qs[0] + __shfl_xor(qs[0], 16, 64);
        int slot = lane & 15;
        int ROW = wm * 32 + (slot & 3) + 8 * (slot >> 2) + rq;
        if ((lane & 16) == 0)
            *reinterpret_cast<float2*>(&pstat[wn][ROW][0]) = make_float2(sum64, sq64);
    }
    __syncthreads();
    if (threadIdx.x < 64) {
        int R = threadIdx.x;
        float s = 0.0f, sq = 0.0f;
        #pragma unroll
        for (int w = 0; w < 4; ++w) {
            float2 p = *reinterpret_cast<float2*>(&pstat[w][R][0]);
            s += p.x; sq += p.y;
        }
        float mean = s * (1.0f / DD);
        float var = sq * (1.0f / DD) - mean * mean;
        float rstd = rsqrtf(var + 1e-5f);
        *reinterpret_cast<float2*>(&stats[R][0]) = make_float2(mean, rstd);
    }
    __syncthreads();

    // normalize + transpose-pack to frags (pad-33 wave-private tiles).
    float* wlds = &tlds[wave][0];
    float mean_r[16], rstd_r[16];
    #pragma unroll
    for (int r = 0; r < 16; ++r) {
        int row = (r & 3) + 8 * (r >> 2) + rq;
        float2 st = *reinterpret_cast<float2*>(&stats[wm * 32 + row][0]);
        mean_r[r] = st.x; rstd_r[r] = st.y;
    }
    for (int j = 0; j < 2; ++j) {
        float gj = lng[n0 + j * 32 + col];
        float bj = lnb[n0 + j * 32 + col];
        #pragma unroll
        for (int r = 0; r < 16; ++r) {
            int row = (r & 3) + 8 * (r >> 2) + rq;
            float v = (acc[j][r] - mean_r[r]) * rstd_r[r] * gj + bj;
            wlds[row * 33 + col] = v;
        }
        #pragma unroll
        for (int it = 0; it < 2; ++it) {
            int task = lane + it * 64;
            int row = task >> 2, cc = task & 3;
            int m = mw + row;
            int k = n0 + j * 32 + cc * 8;
            float* p = &wlds[row * 33 + cc * 8];
            unsigned short us[8];
            #pragma unroll
            for (int e = 0; e < 8; ++e) us[e] = f2bf(p[e]);
            int chunk = ((m >> 5) * (DD >> 4) + (k >> 4)) * 64 + ((k >> 3) & 1) * 32 + (m & 31);
            *reinterpret_cast<uint4*>(out_frag + (size_t)chunk * 8) = *reinterpret_cast<uint4*>(us);
        }
    }
}

// One wave per point. lane = h*16+s; dims d0 = h*64+s*4.
// Distributed scores; pe handled algebraically. kv rows: 512 B fp8.
// R12: score reduction via butterfly reduce-scatter (15 shfl vs 64).
__global__ __launch_bounds__(256) void attn_kernel(
        const unsigned short* __restrict__ q, const unsigned char* __restrict__ kv,
        const float* __restrict__ coord, const float* __restrict__ ctx_coord,
        const int* __restrict__ knn,
        const float* __restrict__ pe_w, const float* __restrict__ pe_b,
        unsigned short* __restrict__ out_frag) {
    int wave = threadIdx.x >> 6, lane = threadIdx.x & 63;
    int m = blockIdx.x * 4 + wave;
    int s = lane & 15;
    int d0 = (lane >> 4) * 64 + s * 4;

    ushort4 qv4 = *reinterpret_cast<const ushort4*>(q + (size_t)m * DD + d0);
    float qx = bf2f(qv4.x), qy = bf2f(qv4.y), qz = bf2f(qv4.z), qw = bf2f(qv4.w);
    float4 pw0 = *reinterpret_cast<const float4*>(pe_w + d0);
    float4 pw1 = *reinterpret_cast<const float4*>(pe_w + DD + d0);
    float4 pw2 = *reinterpret_cast<const float4*>(pe_w + 2 * DD + d0);
    float4 pbv = *reinterpret_cast<const float4*>(pe_b + d0);

    float cx = coord[m * 3], cy = coord[m * 3 + 1], cz = coord[m * 3 + 2];
    int myidx = knn[(size_t)m * KK + s];
    int icm = myidx < 0 ? 0 : myidx;
    float rx = cx - ctx_coord[icm * 3];
    float ry = cy - ctx_coord[icm * 3 + 1];
    float rz = cz - ctx_coord[icm * 3 + 2];

    float t0 = qx * pw0.x + qy * pw0.y + qz * pw0.z + qw * pw0.w;
    float t1 = qx * pw1.x + qy * pw1.y + qz * pw1.z + qw * pw1.w;
    float t2 = qx * pw2.x + qy * pw2.y + qz * pw2.z + qw * pw2.w;
    float t3 = qx * pbv.x + qy * pbv.y + qz * pbv.z + qw * pbv.w;
    #pragma unroll
    for (int o = 1; o < 16; o <<= 1) {
        t0 += __shfl_xor(t0, o, 64);
        t1 += __shfl_xor(t1, o, 64);
        t2 += __shfl_xor(t2, o, 64);
        t3 += __shfl_xor(t3, o, 64);
    }

    // per-lane partials for all 16 scores, then one butterfly reduce-scatter
    float P[KK];
    unsigned vpk[KK];
    #pragma unroll
    for (int j = 0; j < KK; ++j) {
        int ij = __shfl(myidx, j, 64);
        int ic = ij < 0 ? 0 : ij;
        uint2 kvv = *reinterpret_cast<const uint2*>(kv + (size_t)ic * 512 + (d0 >> 2) * 8);
        vpk[j] = kvv.y;
        f32x2 k01 = __builtin_amdgcn_cvt_pk_f32_fp8(kvv.x, false);
        f32x2 k23 = __builtin_amdgcn_cvt_pk_f32_fp8(kvv.x, true);
        P[j] = qx * k01.x + qy * k01.y + qz * k23.x + qw * k23.y;
    }
    redstage<1, 16>(P, lane);
    redstage<2, 8>(P, lane);
    redstage<4, 4>(P, lane);
    redstage<8, 2>(P, lane);
    float corr = rx * t0 + ry * t1 + rz * t2 + t3;
    float sc_own = (myidx >= 0) ? (P[0] + corr) * 0.125f : -1e9f;

    float mx = sc_own;
    mx = fmaxf(mx, __shfl_xor(mx, 1, 64));
    mx = fmaxf(mx, __shfl_xor(mx, 2, 64));
    mx = fmaxf(mx, __shfl_xor(mx, 4, 64));
    mx = fmaxf(mx, __shfl_xor(mx, 8, 64));
    float e = __expf(sc_own - mx);
    float sum = e;
    sum += __shfl_xor(sum, 1, 64);
    sum += __shfl_xor(sum, 2, 64);
    sum += __shfl_xor(sum, 4, 64);
    sum += __shfl_xor(sum, 8, 64);
    float w_own = e * __frcp_rn(sum);

    float wrx = w_own * rx, wry = w_own * ry, wrz = w_own * rz;
    #pragma unroll
    for (int o = 1; o < 16; o <<= 1) {
        wrx += __shfl_xor(wrx, o, 64);
        wry += __shfl_xor(wry, o, 64);
        wrz += __shfl_xor(wrz, o, 64);
    }

    int gbase = lane & 48;
    float ax = 0.f, ay = 0.f, az = 0.f, aw = 0.f;
    #pragma unroll
    for (int j = 0; j < KK; ++j) {
        float wj = __shfl(w_own, gbase + j, 64);
        f32x2 v01 = __builtin_amdgcn_cvt_pk_f32_fp8(vpk[j], false);
        f32x2 v23 = __builtin_amdgcn_cvt_pk_f32_fp8(vpk[j], true);
        ax += wj * v01.x;
        ay += wj * v01.y;
        az += wj * v23.x;
        aw += wj * v23.y;
    }
    ax += wrx * pw0.x + wry * pw1.x + wrz * pw2.x + pbv.x;
    ay += wrx * pw0.y + wry * pw1.y + wrz * pw2.y + pbv.y;
    az += wrx * pw0.z + wry * pw1.z + wrz * pw2.z + pbv.z;
    aw += wrx * pw0.w + wry * pw1.w + wrz * pw2.w + pbv.w;

    ushort4 o4 = make_ushort4(f2bf(ax), f2bf(ay), f2bf(az), f2bf(aw));
    int chunk = ((m >> 5) * (DD >> 4) + (d0 >> 4)) * 64 + ((d0 >> 3) & 1) * 32 + (m & 31);
    *reinterpret_cast<ushort4*>(out_frag + (size_t)chunk * 8 + (d0 & 7)) = o4;
}

extern "C" void kernel_launch(void* const* d_in, const int* in_sizes, int n_in,
                              void* d_out, int out_size, void* d_ws, size_t ws_size,
                              hipStream_t stream) {
    const float* feat_a = (const float*)d_in[0];
    const float* coord_a = (const float*)d_in[1];
    const float* feat_b = (const float*)d_in[2];
    const float* coord_b = (const float*)d_in[3];
    const float* Wq = (const float*)d_in[4];
    const float* Wk = (const float*)d_in[5];
    const float* Wv = (const float*)d_in[6];
    const float* Wo = (const float*)d_in[7];
    const float* ln1_g = (const float*)d_in[8];
    const float* ln1_b = (const float*)d_in[9];
    const float* pe_w = (const float*)d_in[10];
    const float* pe_b = (const float*)d_in[11];
    const float* W1 = (const float*)d_in[12];
    const float* b1 = (const float*)d_in[13];
    const float* W2 = (const float*)d_in[14];
    const float* b2 = (const float*)d_in[15];
    const float* ln2_g = (const float*)d_in[16];
    const float* ln2_b = (const float*)d_in[17];
    const int* knn_a2a = (const int*)d_in[18];
    const int* knn_a2b = (const int*)d_in[19];

    char* ws = (char*)d_ws;
    unsigned short* wfrag = (unsigned short*)ws;                  // 3 MB (4 MB region)
    float* xmid = (float*)(ws + (4ull << 20));                    // 16 MB
    float* xout0 = (float*)(ws + (20ull << 20));                  // 16 MB
    unsigned short* qbuf = (unsigned short*)(ws + (36ull << 20)); // 8 MB
    unsigned char* kvbuf = (unsigned char*)(ws + (52ull << 20));  // 8 MB (fp8)
    unsigned short* xnf = (unsigned short*)(ws + (68ull << 20));  // 8 MB
    unsigned short* ctxfa = (unsigned short*)(ws + (76ull << 20));// 8 MB
    unsigned short* attnf = (unsigned short*)(ws + (84ull << 20));// 8 MB
    unsigned short* ctxfb = (unsigned short*)(ws + (92ull << 20));// 8 MB -> 100 MB
    unsigned short* geluf = (unsigned short*)(ws + (36ull << 20));// 32 MB, overlays q/kv (dead by FFN)

    const unsigned short* WQF = wfrag;
    const unsigned short* KVF = wfrag + 131072;
    const unsigned short* WOF = wfrag + 393216;
    const unsigned short* W1F = wfrag + 524288;
    const unsigned short* W2F = wfrag + 1048576;

    prep_weights<<<(1572864 + 255) / 256, 256, 0, stream>>>(Wq, Wk, Wv, Wo, W1, W2, wfrag);

    // one launch: xnf = LN1(feat_a); ctxfa = conv(feat_a); ctxfb = conv(feat_b)
    ln3_to_frag<<<dim3(MM / 4, 3), 256, 0, stream>>>(feat_a, ln1_g, ln1_b, feat_b,
                                                     xnf, ctxfa, ctxfb);

    // ---- block 0: self(a) ----
    gemm_qkv<<<768, 256, 0, stream>>>(
        (const bf16x8*)xnf, (const bf16x8*)ctxfa,
        (const bf16x8*)WQF, (const bf16x8*)KVF, qbuf, kvbuf);

    attn_kernel<<<MM / 4, 256, 0, stream>>>(qbuf, kvbuf, coord_a, coord_a, knn_a2a,
                                            pe_w, pe_b, attnf);

    // Wo-GEMM + resid + LN2 -> xmid (f32) and xnf (frags)
    gemm_ln<256, false><<<MM / 64, 512, 0, stream>>>(
        (const bf16x8*)attnf, (const bf16x8*)WOF, xmid, feat_a, nullptr,
        ln2_g, ln2_b, xnf);

    // FFN1+GELU: XCD-swizzled, 64x128 wg tiles, 1D grid 2048
    gemm_gelu<<<2048, 256, 0, stream>>>(
        (const bf16x8*)xnf, (const bf16x8*)W1F, geluf, b1, 1024);

    // FFN2 + resid + LN1(blk1) -> xout0 (f32) and xnf (frags for blk1 Q-proj)
    gemm_ln<1024, true><<<MM / 64, 512, 0, stream>>>(
        (const bf16x8*)geluf, (const bf16x8*)W2F, xout0, xmid, b2,
        ln1_g + DD, ln1_b + DD, xnf);

    // ---- block 1: cross(a,b) ----
    gemm_qkv<<<768, 256, 0, stream>>>(
        (const bf16x8*)xnf, (const bf16x8*)ctxfb,
        (const bf16x8*)(WQF + 65536), (const bf16x8*)(KVF + 131072), qbuf, kvbuf);

    attn_kernel<<<MM / 4, 256, 0, stream>>>(qbuf, kvbuf, coord_a, coord_b, knn_a2b,
                                            pe_w + 3 * DD, pe_b + DD, attnf);

    gemm_ln<256, false><<<MM / 64, 512, 0, stream>>>(
        (const bf16x8*)attnf, (const bf16x8*)(WOF + 65536), xmid, xout0, nullptr,
        ln2_g + DD, ln2_b + DD, xnf);

    gemm_gelu<<<2048, 256, 0, stream>>>(
        (const bf16x8*)xnf, (const bf16x8*)(W1F + 262144), geluf, b1 + DFF_, 1024);

    // final FFN2: XCD-swizzled, 64x128 tiles, 1D grid 512
    gemm_frag64<1024, 256, true, true><<<512, 256, 0, stream>>>(
        (const bf16x8*)geluf, (const bf16x8*)(W2F + 262144), (float*)d_out, xmid,
        b2 + DD);
}

// Round 12
// 307.549 us; speedup vs baseline: 1.0347x; 1.0123x over previous
//
#include <hip/hip_runtime.h>
#include <hip/hip_bf16.h>
#include <stdint.h>

#define MM 16384
#define DD 256
#define HH 4
#define KK 16
#define DFF_ 1024

typedef __attribute__((ext_vector_type(8))) short bf16x8;
typedef __attribute__((ext_vector_type(16))) float f32x16;
typedef __attribute__((ext_vector_type(2))) float f32x2;

__device__ __forceinline__ unsigned short f2bf(float f) {
    unsigned u = __builtin_bit_cast(unsigned, f);
    unsigned r = u + 0x7fffu + ((u >> 16) & 1u);
    return (unsigned short)(r >> 16);
}
__device__ __forceinline__ float bf2f(unsigned short h) {
    unsigned u = ((unsigned)h) << 16;
    return __builtin_bit_cast(float, u);
}

// ---------------------------------------------------------------------------
// Fragment layouts (bf16, 16B chunks of 8 elems; fp8, 8B chunks of 8 elems):
// A-frag (row m, k):  chunk = ((m>>5)*(KD/16) + (k>>4))*64 + ((k>>3)&1)*32 + (m&31), elem = k&7
// B-frag (col n, k):  same with n. fp8 uses the same logical mapping, 1B/elem.
// v_mfma_f32_32x32x16_bf16 C/D: col=lane&31, row=(reg&3)+8*(reg>>2)+4*(lane>>5)
// kv buffer: fp8 e4m3 rows of 512 B, groups of 8 B = [K4 | V4].
// NOTE (R14): grid-starvation lever (335.7->311.8). R15: 64-col min B-reuse.
// NOTE (R16-R20): ~180TF GEMM wall survives occupancy/pipeline/in-flight/
//   staging/fusion/XCD-swizzle. Two surviving models: per-CU VMEM BYTE cap
//   (~13B/cyc/CU) vs instruction/latency structure. Discriminator: fp8.
// NOTE (R21/this round): FFN1 in fp8 e4m3 (mfma_f32_32x32x16_fp8_fp8):
//   same MFMA count, same load count, HALF the operand bytes. W1 pre-scaled
//   x32 into e4m3 normal range (acc de-scaled 1/32). xn (LN out, ~N(0,1))
//   packed to fp8 by gemm_ln<...,FP8OUT=true>. Gives up bit-exactness:
//   expected absmax 0.04-0.07. If dur ~halves on FFN1 -> byte-cap confirmed,
//   roll fp8 out further. If flat -> revert, declare bf16 floor.
// ---------------------------------------------------------------------------

// wfrag layout (shorts): WQF@0 (blk stride 65536), KVF@131072 (131072),
//   WOF@393216 (65536), [old W1F region unused], W2F@1048576 (262144);
//   W1F8 (fp8, x32) at BYTE offset 3145728, blk stride 262144 B.
__global__ __launch_bounds__(256) void prep_weights(
        const float* __restrict__ Wq, const float* __restrict__ Wk,
        const float* __restrict__ Wv, const float* __restrict__ Wo,
        const float* __restrict__ W1, const float* __restrict__ W2,
        unsigned short* __restrict__ wf) {
    int t = blockIdx.x * blockDim.x + threadIdx.x;
    const float* src; unsigned short* dst = nullptr;
    int kd, lg, rem, blk, e, sect;
    if (t < 131072) { sect = 0; rem = t; blk = rem >> 16; e = rem & 65535;
        src = Wq; dst = wf + blk * 65536; kd = 256; lg = 8; }
    else if (t < 262144) { sect = 1; rem = t - 131072; blk = rem >> 16; e = rem & 65535;
        src = Wk; dst = wf + 131072 + blk * 131072; kd = 256; lg = 8; }
    else if (t < 393216) { sect = 2; rem = t - 262144; blk = rem >> 16; e = rem & 65535;
        src = Wv; dst = wf + 131072 + blk * 131072; kd = 256; lg = 8; }
    else if (t < 524288) { sect = 0; rem = t - 393216; blk = rem >> 16; e = rem & 65535;
        src = Wo; dst = wf + 393216 + blk * 65536; kd = 256; lg = 8; }
    else if (t < 1048576) { sect = 3; rem = t - 524288; blk = rem >> 18; e = rem & 262143;
        src = W1; kd = 256; lg = 10; }
    else if (t < 1572864) { sect = 0; rem = t - 1048576; blk = rem >> 18; e = rem & 262143;
        src = W2; dst = wf + 1048576 + blk * 262144; kd = 1024; lg = 8; }
    else return;
    int k = e >> lg;
    int n = e & ((1 << lg) - 1);
    if (sect == 1) n = (n >> 2) * 8 + (n & 3);
    else if (sect == 2) n = (n >> 2) * 8 + 4 + (n & 3);
    float v = src[(size_t)blk * kd * (1 << lg) + e];
    int off = ((n >> 5) * (kd >> 4) + (k >> 4)) * 512 + (((k >> 3) & 1) * 32 + (n & 31)) * 8 + (k & 7);
    if (sect == 3) {
        unsigned char* d8 = ((unsigned char*)wf) + 3145728 + blk * 262144;
        float vs = v * 32.0f;
        d8[off] = (unsigned char)(__builtin_amdgcn_cvt_pk_fp8_f32(vs, vs, 0, false) & 0xff);
    } else {
        dst[off] = f2bf(v);
    }
}

// 3 slices in one launch: y=0: LN(xa,g,b)->outln; y=1: conv(xa)->outca; y=2: conv(xb)->outcb
__global__ __launch_bounds__(256) void ln3_to_frag(
        const float* __restrict__ xa, const float* __restrict__ g,
        const float* __restrict__ b, const float* __restrict__ xb,
        unsigned short* __restrict__ outln, unsigned short* __restrict__ outca,
        unsigned short* __restrict__ outcb) {
    int y = blockIdx.y;
    const float* x = (y == 2) ? xb : xa;
    unsigned short* out = (y == 0) ? outln : (y == 1 ? outca : outcb);
    int apply_ln = (y == 0);
    int wave = threadIdx.x >> 6, lane = threadIdx.x & 63;
    int m = blockIdx.x * 4 + wave;
    const float4 xv = reinterpret_cast<const float4*>(x + (size_t)m * DD)[lane];
    float vals[4] = {xv.x, xv.y, xv.z, xv.w};
    int k0 = lane * 4;
    if (apply_ln) {
        float s = vals[0] + vals[1] + vals[2] + vals[3];
        float sq = vals[0]*vals[0] + vals[1]*vals[1] + vals[2]*vals[2] + vals[3]*vals[3];
        for (int o = 32; o; o >>= 1) { s += __shfl_xor(s, o, 64); sq += __shfl_xor(sq, o, 64); }
        float mean = s * (1.0f / DD);
        float var = sq * (1.0f / DD) - mean * mean;
        float rs = rsqrtf(var + 1e-5f);
        #pragma unroll
        for (int c = 0; c < 4; ++c)
            vals[c] = (vals[c] - mean) * rs * g[k0 + c] + b[k0 + c];
    }
    int chunk = ((m >> 5) * (DD >> 4) + (k0 >> 4)) * 64 + ((k0 >> 3) & 1) * 32 + (m & 31);
    ushort4 o4 = make_ushort4(f2bf(vals[0]), f2bf(vals[1]), f2bf(vals[2]), f2bf(vals[3]));
    *reinterpret_cast<ushort4*>(out + (size_t)chunk * 8 + (k0 & 7)) = o4;
}

template <int KG>
__device__ __forceinline__ void compute_tile(
        const bf16x8* __restrict__ a0, const bf16x8* __restrict__ a1,
        const bf16x8* __restrict__ b0, const bf16x8* __restrict__ b1,
        f32x16 acc[2][2]) {
    #pragma unroll 4
    for (int g = 0; g < KG; ++g) {
        bf16x8 av0 = a0[g * 64];
        bf16x8 av1 = a1[g * 64];
        bf16x8 bv0 = b0[g * 64];
        bf16x8 bv1 = b1[g * 64];
        acc[0][0] = __builtin_amdgcn_mfma_f32_32x32x16_bf16(av0, bv0, acc[0][0], 0, 0, 0);
        acc[0][1] = __builtin_amdgcn_mfma_f32_32x32x16_bf16(av0, bv1, acc[0][1], 0, 0, 0);
        acc[1][0] = __builtin_amdgcn_mfma_f32_32x32x16_bf16(av1, bv0, acc[1][0], 0, 0, 0);
        acc[1][1] = __builtin_amdgcn_mfma_f32_32x32x16_bf16(av1, bv1, acc[1][1], 0, 0, 0);
    }
}

// R21: FFN1 + GELU in FP8. wg = 64x128 (4 waves 2m x 2n of 32x64), XCD
// swizzle as R20. A (xn fp8) and B (W1 fp8, pre-scaled x32) are 8B/lane
// chunks; acc de-scaled by 1/32 in epilogue. Same MFMA/load counts as bf16,
// HALF the operand bytes.
__global__ __launch_bounds__(256) void gemm_gelu_f8(
        const unsigned char* __restrict__ A8, const unsigned char* __restrict__ B8,
        unsigned short* __restrict__ outp, const float* __restrict__ bias,
        int out_kd) {
    constexpr int KG = 16;
    __shared__ float lds[4 * 1056];
    int wave = threadIdx.x >> 6, lane = threadIdx.x & 63;
    int wm = wave & 1, wn = wave >> 1;
    int id = blockIdx.x;
    int xcd = id & 7, slot = id >> 3;
    int bx = 32 * xcd + (slot & 31);
    int by = slot >> 5;
    int mw = bx * 64 + wm * 32;
    int nw = by * 128 + wn * 64;
    const uint2* a0 = (const uint2*)A8 + ((size_t)(mw >> 5) * KG) * 64 + lane;
    const uint2* b0 = (const uint2*)B8 + ((size_t)(nw >> 5) * KG) * 64 + lane;
    const uint2* b1 = b0 + (size_t)KG * 64;
    f32x16 acc[2] = {};
    #pragma unroll 4
    for (int g = 0; g < KG; ++g) {
        long av  = __builtin_bit_cast(long, a0[g * 64]);
        long bv0 = __builtin_bit_cast(long, b0[g * 64]);
        long bv1 = __builtin_bit_cast(long, b1[g * 64]);
        acc[0] = __builtin_amdgcn_mfma_f32_32x32x16_fp8_fp8(av, bv0, acc[0], 0, 0, 0);
        acc[1] = __builtin_amdgcn_mfma_f32_32x32x16_fp8_fp8(av, bv1, acc[1], 0, 0, 0);
    }
    int col = lane & 31, rq = (lane >> 5) * 4;
    float* wlds = &lds[wave * 1056];
    for (int j = 0; j < 2; ++j) {
        #pragma unroll
        for (int r = 0; r < 16; ++r) {
            int row = (r & 3) + 8 * (r >> 2) + rq;
            int n = nw + j * 32 + col;
            float v = acc[j][r] * (1.0f / 32.0f) + bias[n];
            float arg = v * (1.5957691216f + 0.0713548163f * v * v);
            v = v * __frcp_rn(1.0f + __expf(-arg));
            wlds[row * 33 + col] = v;
        }
        #pragma unroll
        for (int it = 0; it < 2; ++it) {
            int task = lane + it * 64;
            int row = task >> 2, cc = task & 3;
            int m = mw + row;
            int k = nw + j * 32 + cc * 8;
            float* p = &wlds[row * 33 + cc * 8];
            unsigned short us[8];
            #pragma unroll
            for (int e = 0; e < 8; ++e) us[e] = f2bf(p[e]);
            int chunk = ((m >> 5) * (out_kd >> 4) + (k >> 4)) * 64 + ((k >> 3) & 1) * 32 + (m & 31);
            reinterpret_cast<uint4*>(outp)[chunk] = *reinterpret_cast<uint4*>(us);
        }
    }
}

// R20 form: final FFN2 with XCD swizzle. 64x128 wg tile, 4 waves 2m x 2n.
template <int KD, int NOUT, bool RESID, bool BIAS>
__global__ __launch_bounds__(256) void gemm_frag64(
        const bf16x8* __restrict__ A, const bf16x8* __restrict__ B,
        float* __restrict__ outp, const float* __restrict__ resid,
        const float* __restrict__ bias) {
    constexpr int KG = KD / 16;
    int wave = threadIdx.x >> 6, lane = threadIdx.x & 63;
    int wm = wave & 1, wn = wave >> 1;
    int id = blockIdx.x;
    int xcd = id & 7, slot = id >> 3;
    int bx = 32 * xcd + (slot >> 1);
    int by = slot & 1;
    int mw = bx * 64 + wm * 32;
    int nw = by * 128 + wn * 64;
    const bf16x8* a0 = A + ((size_t)(mw >> 5) * KG) * 64 + lane;
    const bf16x8* b0 = B + ((size_t)(nw >> 5) * KG) * 64 + lane;
    const bf16x8* b1 = b0 + (size_t)KG * 64;
    f32x16 acc[2] = {};
    #pragma unroll 4
    for (int g = 0; g < KG; ++g) {
        bf16x8 av = a0[g * 64];
        bf16x8 bv0 = b0[g * 64];
        bf16x8 bv1 = b1[g * 64];
        acc[0] = __builtin_amdgcn_mfma_f32_32x32x16_bf16(av, bv0, acc[0], 0, 0, 0);
        acc[1] = __builtin_amdgcn_mfma_f32_32x32x16_bf16(av, bv1, acc[1], 0, 0, 0);
    }
    int col = lane & 31, rq = (lane >> 5) * 4;
    #pragma unroll
    for (int j = 0; j < 2; ++j) {
        #pragma unroll
        for (int r = 0; r < 16; ++r) {
            int row = (r & 3) + 8 * (r >> 2) + rq;
            int m = mw + row;
            int n = nw + j * 32 + col;
            float v = acc[j][r];
            if (BIAS) v += bias[n];
            if (RESID) v += resid[(size_t)m * NOUT + n];
            outp[(size_t)m * NOUT + n] = v;
        }
    }
}

// R20 form: fused Q + KV projections with XCD swizzle. 128x128 wg tiles.
__global__ __launch_bounds__(256) void gemm_qkv(
        const bf16x8* __restrict__ Aq, const bf16x8* __restrict__ Akv,
        const bf16x8* __restrict__ Bq, const bf16x8* __restrict__ Bkv,
        unsigned short* __restrict__ qout, unsigned char* __restrict__ kvout) {
    constexpr int KG = 16;
    int wave = threadIdx.x >> 6, lane = threadIdx.x & 63;
    int wm = wave & 1, wn = wave >> 1;
    int id = blockIdx.x;
    int xcd = id & 7, slot = id >> 3;
    int bx = 16 * xcd + (slot & 15);
    int y = slot >> 4;
    bool isQ = y < 2;
    const bf16x8* A = isQ ? Aq : Akv;
    const bf16x8* B = isQ ? Bq : Bkv;
    int n0 = (isQ ? y : y - 2) * 128 + wn * 64;
    int m0 = bx * 128 + wm * 64;
    const bf16x8* a0 = A + ((size_t)(m0 >> 5) * KG) * 64 + lane;
    const bf16x8* a1 = a0 + (size_t)KG * 64;
    const bf16x8* b0 = B + ((size_t)(n0 >> 5) * KG) * 64 + lane;
    const bf16x8* b1 = b0 + (size_t)KG * 64;
    f32x16 acc[2][2] = {};
    compute_tile<KG>(a0, a1, b0, b1, acc);
    int col = lane & 31, rq = (lane >> 5) * 4;
    #pragma unroll
    for (int i = 0; i < 2; ++i)
    #pragma unroll
    for (int j = 0; j < 2; ++j)
    #pragma unroll
    for (int r = 0; r < 16; ++r) {
        int row = (r & 3) + 8 * (r >> 2) + rq;
        int m = m0 + i * 32 + row;
        int n = n0 + j * 32 + col;
        float v = acc[i][j][r];
        if (isQ) qout[(size_t)m * 256 + n] = f2bf(v);
        else kvout[(size_t)m * 512 + n] =
            (unsigned char)(__builtin_amdgcn_cvt_pk_fp8_f32(v, v, 0, false) & 0xff);
    }
}

// butterfly reduce-scatter stage: N slots -> N/2 slots (xor-butterfly).
template <int O, int N>
__device__ __forceinline__ void redstage(float* a, int lane) {
    int sel = lane & O;
    #pragma unroll
    for (int u = 0; u < N / 2; ++u) {
        float lo = a[2 * u], hi = a[2 * u + 1];
        float keep = sel ? hi : lo;
        float send = sel ? lo : hi;
        a[u] = keep + __shfl_xor(send, O, 64);
    }
}

// Fused GEMM(+bias)+resid -> f32 C; LayerNorm rows -> A-frag output.
// FP8OUT=false: bf16 frags (16B chunks). FP8OUT=true: fp8 e4m3 frags
// (8B chunks) for the fp8 FFN1.
template <int KD, bool BIAS, bool FP8OUT>
__global__ __launch_bounds__(512) void gemm_ln(
        const bf16x8* __restrict__ A, const bf16x8* __restrict__ B,
        float* __restrict__ out_f32, const float* __restrict__ resid,
        const float* __restrict__ bias,
        const float* __restrict__ lng, const float* __restrict__ lnb,
        unsigned short* __restrict__ out_frag) {
    constexpr int KG = KD / 16;
    __shared__ float pstat[4][64][2];   // [wn][block row][sum,sumsq]
    __shared__ float stats[64][2];      // [block row][mean, rstd]
    __shared__ float tlds[8][32 * 33];  // per-wave transpose pads
    int wave = threadIdx.x >> 6, lane = threadIdx.x & 63;
    int wm = wave >> 2, wn = wave & 3;
    int m0 = blockIdx.x * 64;
    int mw = m0 + wm * 32;
    int n0 = wn * 64;
    const bf16x8* a0 = A + ((size_t)(mw >> 5) * KG) * 64 + lane;
    const bf16x8* b0 = B + ((size_t)(n0 >> 5) * KG) * 64 + lane;
    const bf16x8* b1 = b0 + (size_t)KG * 64;
    f32x16 acc[2] = {};
    #pragma unroll 4
    for (int g = 0; g < KG; ++g) {
        bf16x8 av = a0[g * 64];
        bf16x8 bv0 = b0[g * 64];
        bf16x8 bv1 = b1[g * 64];
        acc[0] = __builtin_amdgcn_mfma_f32_32x32x16_bf16(av, bv0, acc[0], 0, 0, 0);
        acc[1] = __builtin_amdgcn_mfma_f32_32x32x16_bf16(av, bv1, acc[1], 0, 0, 0);
    }
    int col = lane & 31, rq = (lane >> 5) * 4;

    // epilogue pass 1: v = acc (+bias) + resid; write f32; stash v in acc.
    #pragma unroll
    for (int j = 0; j < 2; ++j) {
        #pragma unroll
        for (int r = 0; r < 16; ++r) {
            int row = (r & 3) + 8 * (r >> 2) + rq;
            int m = mw + row;
            int n = n0 + j * 32 + col;
            float v = acc[j][r];
            if (BIAS) v += bias[n];
            v += resid[(size_t)m * DD + n];
            out_f32[(size_t)m * DD + n] = v;
            acc[j][r] = v;
        }
    }

    // per-wave row sums over this wave's 64 cols (16 slots, 4 stages + xor16).
    {
        float ps[16];
        #pragma unroll
        for (int r = 0; r < 16; ++r)
            ps[r] = acc[0][r] + acc[1][r];
        redstage<1, 16>(ps, lane);
        redstage<2, 8>(ps, lane);
        redstage<4, 4>(ps, lane);
        redstage<8, 2>(ps, lane);
        float sum64 = ps[0] + __shfl_xor(ps[0], 16, 64);
        float qs[16];
        #pragma unroll
        for (int r = 0; r < 16; ++r) {
            float a = acc[0][r], b = acc[1][r];
            qs[r] = a * a + b * b;
        }
        redstage<1, 16>(qs, lane);
        redstage<2, 8>(qs, lane);
        redstage<4, 4>(qs, lane);
        redstage<8, 2>(qs, lane);
        float sq64 = qs[0] + __shfl_xor(qs[0], 16, 64);
        int slot = lane & 15;
        int ROW = wm * 32 + (slot & 3) + 8 * (slot >> 2) + rq;
        if ((lane & 16) == 0)
            *reinterpret_cast<float2*>(&pstat[wn][ROW][0]) = make_float2(sum64, sq64);
    }
    __syncthreads();
    if (threadIdx.x < 64) {
        int R = threadIdx.x;
        float s = 0.0f, sq = 0.0f;
        #pragma unroll
        for (int w = 0; w < 4; ++w) {
            float2 p = *reinterpret_cast<float2*>(&pstat[w][R][0]);
            s += p.x; sq += p.y;
        }
        float mean = s * (1.0f / DD);
        float var = sq * (1.0f / DD) - mean * mean;
        float rstd = rsqrtf(var + 1e-5f);
        *reinterpret_cast<float2*>(&stats[R][0]) = make_float2(mean, rstd);
    }
    __syncthreads();

    // normalize + transpose-pack to frags (pad-33 wave-private tiles).
    float* wlds = &tlds[wave][0];
    float mean_r[16], rstd_r[16];
    #pragma unroll
    for (int r = 0; r < 16; ++r) {
        int row = (r & 3) + 8 * (r >> 2) + rq;
        float2 st = *reinterpret_cast<float2*>(&stats[wm * 32 + row][0]);
        mean_r[r] = st.x; rstd_r[r] = st.y;
    }
    for (int j = 0; j < 2; ++j) {
        float gj = lng[n0 + j * 32 + col];
        float bj = lnb[n0 + j * 32 + col];
        #pragma unroll
        for (int r = 0; r < 16; ++r) {
            int row = (r & 3) + 8 * (r >> 2) + rq;
            float v = (acc[j][r] - mean_r[r]) * rstd_r[r] * gj + bj;
            wlds[row * 33 + col] = v;
        }
        #pragma unroll
        for (int it = 0; it < 2; ++it) {
            int task = lane + it * 64;
            int row = task >> 2, cc = task & 3;
            int m = mw + row;
            int k = n0 + j * 32 + cc * 8;
            float* p = &wlds[row * 33 + cc * 8];
            int chunk = ((m >> 5) * (DD >> 4) + (k >> 4)) * 64 + ((k >> 3) & 1) * 32 + (m & 31);
            if constexpr (FP8OUT) {
                unsigned w0 = __builtin_amdgcn_cvt_pk_fp8_f32(p[0], p[1], 0, false);
                w0 = __builtin_amdgcn_cvt_pk_fp8_f32(p[2], p[3], w0, true);
                unsigned w1 = __builtin_amdgcn_cvt_pk_fp8_f32(p[4], p[5], 0, false);
                w1 = __builtin_amdgcn_cvt_pk_fp8_f32(p[6], p[7], w1, true);
                *reinterpret_cast<uint2*>((unsigned char*)out_frag + (size_t)chunk * 8) =
                    make_uint2(w0, w1);
            } else {
                unsigned short us[8];
                #pragma unroll
                for (int e = 0; e < 8; ++e) us[e] = f2bf(p[e]);
                *reinterpret_cast<uint4*>(out_frag + (size_t)chunk * 8) = *reinterpret_cast<uint4*>(us);
            }
        }
    }
}

// One wave per point. lane = h*16+s; dims d0 = h*64+s*4.
// Distributed scores; pe handled algebraically. kv rows: 512 B fp8.
__global__ __launch_bounds__(256) void attn_kernel(
        const unsigned short* __restrict__ q, const unsigned char* __restrict__ kv,
        const float* __restrict__ coord, const float* __restrict__ ctx_coord,
        const int* __restrict__ knn,
        const float* __restrict__ pe_w, const float* __restrict__ pe_b,
        unsigned short* __restrict__ out_frag) {
    int wave = threadIdx.x >> 6, lane = threadIdx.x & 63;
    int m = blockIdx.x * 4 + wave;
    int s = lane & 15;
    int d0 = (lane >> 4) * 64 + s * 4;

    ushort4 qv4 = *reinterpret_cast<const ushort4*>(q + (size_t)m * DD + d0);
    float qx = bf2f(qv4.x), qy = bf2f(qv4.y), qz = bf2f(qv4.z), qw = bf2f(qv4.w);
    float4 pw0 = *reinterpret_cast<const float4*>(pe_w + d0);
    float4 pw1 = *reinterpret_cast<const float4*>(pe_w + DD + d0);
    float4 pw2 = *reinterpret_cast<const float4*>(pe_w + 2 * DD + d0);
    float4 pbv = *reinterpret_cast<const float4*>(pe_b + d0);

    float cx = coord[m * 3], cy = coord[m * 3 + 1], cz = coord[m * 3 + 2];
    int myidx = knn[(size_t)m * KK + s];
    int icm = myidx < 0 ? 0 : myidx;
    float rx = cx - ctx_coord[icm * 3];
    float ry = cy - ctx_coord[icm * 3 + 1];
    float rz = cz - ctx_coord[icm * 3 + 2];

    float t0 = qx * pw0.x + qy * pw0.y + qz * pw0.z + qw * pw0.w;
    float t1 = qx * pw1.x + qy * pw1.y + qz * pw1.z + qw * pw1.w;
    float t2 = qx * pw2.x + qy * pw2.y + qz * pw2.z + qw * pw2.w;
    float t3 = qx * pbv.x + qy * pbv.y + qz * pbv.z + qw * pbv.w;
    #pragma unroll
    for (int o = 1; o < 16; o <<= 1) {
        t0 += __shfl_xor(t0, o, 64);
        t1 += __shfl_xor(t1, o, 64);
        t2 += __shfl_xor(t2, o, 64);
        t3 += __shfl_xor(t3, o, 64);
    }

    // per-lane partials for all 16 scores, then one butterfly reduce-scatter
    float P[KK];
    unsigned vpk[KK];
    #pragma unroll
    for (int j = 0; j < KK; ++j) {
        int ij = __shfl(myidx, j, 64);
        int ic = ij < 0 ? 0 : ij;
        uint2 kvv = *reinterpret_cast<const uint2*>(kv + (size_t)ic * 512 + (d0 >> 2) * 8);
        vpk[j] = kvv.y;
        f32x2 k01 = __builtin_amdgcn_cvt_pk_f32_fp8(kvv.x, false);
        f32x2 k23 = __builtin_amdgcn_cvt_pk_f32_fp8(kvv.x, true);
        P[j] = qx * k01.x + qy * k01.y + qz * k23.x + qw * k23.y;
    }
    redstage<1, 16>(P, lane);
    redstage<2, 8>(P, lane);
    redstage<4, 4>(P, lane);
    redstage<8, 2>(P, lane);
    float corr = rx * t0 + ry * t1 + rz * t2 + t3;
    float sc_own = (myidx >= 0) ? (P[0] + corr) * 0.125f : -1e9f;

    float mx = sc_own;
    mx = fmaxf(mx, __shfl_xor(mx, 1, 64));
    mx = fmaxf(mx, __shfl_xor(mx, 2, 64));
    mx = fmaxf(mx, __shfl_xor(mx, 4, 64));
    mx = fmaxf(mx, __shfl_xor(mx, 8, 64));
    float e = __expf(sc_own - mx);
    float sum = e;
    sum += __shfl_xor(sum, 1, 64);
    sum += __shfl_xor(sum, 2, 64);
    sum += __shfl_xor(sum, 4, 64);
    sum += __shfl_xor(sum, 8, 64);
    float w_own = e * __frcp_rn(sum);

    float wrx = w_own * rx, wry = w_own * ry, wrz = w_own * rz;
    #pragma unroll
    for (int o = 1; o < 16; o <<= 1) {
        wrx += __shfl_xor(wrx, o, 64);
        wry += __shfl_xor(wry, o, 64);
        wrz += __shfl_xor(wrz, o, 64);
    }

    int gbase = lane & 48;
    float ax = 0.f, ay = 0.f, az = 0.f, aw = 0.f;
    #pragma unroll
    for (int j = 0; j < KK; ++j) {
        float wj = __shfl(w_own, gbase + j, 64);
        f32x2 v01 = __builtin_amdgcn_cvt_pk_f32_fp8(vpk[j], false);
        f32x2 v23 = __builtin_amdgcn_cvt_pk_f32_fp8(vpk[j], true);
        ax += wj * v01.x;
        ay += wj * v01.y;
        az += wj * v23.x;
        aw += wj * v23.y;
    }
    ax += wrx * pw0.x + wry * pw1.x + wrz * pw2.x + pbv.x;
    ay += wrx * pw0.y + wry * pw1.y + wrz * pw2.y + pbv.y;
    az += wrx * pw0.z + wry * pw1.z + wrz * pw2.z + pbv.z;
    aw += wrx * pw0.w + wry * pw1.w + wrz * pw2.w + pbv.w;

    ushort4 o4 = make_ushort4(f2bf(ax), f2bf(ay), f2bf(az), f2bf(aw));
    int chunk = ((m >> 5) * (DD >> 4) + (d0 >> 4)) * 64 + ((d0 >> 3) & 1) * 32 + (m & 31);
    *reinterpret_cast<ushort4*>(out_frag + (size_t)chunk * 8 + (d0 & 7)) = o4;
}

extern "C" void kernel_launch(void* const* d_in, const int* in_sizes, int n_in,
                              void* d_out, int out_size, void* d_ws, size_t ws_size,
                              hipStream_t stream) {
    const float* feat_a = (const float*)d_in[0];
    const float* coord_a = (const float*)d_in[1];
    const float* feat_b = (const float*)d_in[2];
    const float* coord_b = (const float*)d_in[3];
    const float* Wq = (const float*)d_in[4];
    const float* Wk = (const float*)d_in[5];
    const float* Wv = (const float*)d_in[6];
    const float* Wo = (const float*)d_in[7];
    const float* ln1_g = (const float*)d_in[8];
    const float* ln1_b = (const float*)d_in[9];
    const float* pe_w = (const float*)d_in[10];
    const float* pe_b = (const float*)d_in[11];
    const float* W1 = (const float*)d_in[12];
    const float* b1 = (const float*)d_in[13];
    const float* W2 = (const float*)d_in[14];
    const float* b2 = (const float*)d_in[15];
    const float* ln2_g = (const float*)d_in[16];
    const float* ln2_b = (const float*)d_in[17];
    const int* knn_a2a = (const int*)d_in[18];
    const int* knn_a2b = (const int*)d_in[19];

    char* ws = (char*)d_ws;
    unsigned short* wfrag = (unsigned short*)ws;                  // 3.5 MB (4 MB region)
    float* xmid = (float*)(ws + (4ull << 20));                    // 16 MB
    float* xout0 = (float*)(ws + (20ull << 20));                  // 16 MB
    unsigned short* qbuf = (unsigned short*)(ws + (36ull << 20)); // 8 MB
    unsigned char* kvbuf = (unsigned char*)(ws + (52ull << 20));  // 8 MB (fp8)
    unsigned short* xnf = (unsigned short*)(ws + (68ull << 20));  // 8 MB
    unsigned short* ctxfa = (unsigned short*)(ws + (76ull << 20));// 8 MB
    unsigned short* attnf = (unsigned short*)(ws + (84ull << 20));// 8 MB
    unsigned short* ctxfb = (unsigned short*)(ws + (92ull << 20));// 8 MB -> 100 MB
    unsigned char* xnf8 = (unsigned char*)(ws + (100ull << 20));  // 4 MB (fp8 xn) -> 104 MB
    unsigned short* geluf = (unsigned short*)(ws + (36ull << 20));// 32 MB, overlays q/kv (dead by FFN)

    const unsigned short* WQF = wfrag;
    const unsigned short* KVF = wfrag + 131072;
    const unsigned short* WOF = wfrag + 393216;
    const unsigned short* W2F = wfrag + 1048576;
    const unsigned char* W1F8 = ((const unsigned char*)wfrag) + 3145728;

    prep_weights<<<(1572864 + 255) / 256, 256, 0, stream>>>(Wq, Wk, Wv, Wo, W1, W2, wfrag);

    // one launch: xnf = LN1(feat_a); ctxfa = conv(feat_a); ctxfb = conv(feat_b)
    ln3_to_frag<<<dim3(MM / 4, 3), 256, 0, stream>>>(feat_a, ln1_g, ln1_b, feat_b,
                                                     xnf, ctxfa, ctxfb);

    // ---- block 0: self(a) ----
    gemm_qkv<<<768, 256, 0, stream>>>(
        (const bf16x8*)xnf, (const bf16x8*)ctxfa,
        (const bf16x8*)WQF, (const bf16x8*)KVF, qbuf, kvbuf);

    attn_kernel<<<MM / 4, 256, 0, stream>>>(qbuf, kvbuf, coord_a, coord_a, knn_a2a,
                                            pe_w, pe_b, attnf);

    // Wo-GEMM + resid + LN2 -> xmid (f32) and xnf8 (fp8 frags for fp8 FFN1)
    gemm_ln<256, false, true><<<MM / 64, 512, 0, stream>>>(
        (const bf16x8*)attnf, (const bf16x8*)WOF, xmid, feat_a, nullptr,
        ln2_g, ln2_b, (unsigned short*)xnf8);

    // FFN1+GELU in fp8: XCD-swizzled, 64x128 wg tiles, 1D grid 2048
    gemm_gelu_f8<<<2048, 256, 0, stream>>>(
        xnf8, W1F8, geluf, b1, 1024);

    // FFN2 + resid + LN1(blk1) -> xout0 (f32) and xnf (bf16 frags for blk1 Q)
    gemm_ln<1024, true, false><<<MM / 64, 512, 0, stream>>>(
        (const bf16x8*)geluf, (const bf16x8*)W2F, xout0, xmid, b2,
        ln1_g + DD, ln1_b + DD, xnf);

    // ---- block 1: cross(a,b) ----
    gemm_qkv<<<768, 256, 0, stream>>>(
        (const bf16x8*)xnf, (const bf16x8*)ctxfb,
        (const bf16x8*)(WQF + 65536), (const bf16x8*)(KVF + 131072), qbuf, kvbuf);

    attn_kernel<<<MM / 4, 256, 0, stream>>>(qbuf, kvbuf, coord_a, coord_b, knn_a2b,
                                            pe_w + 3 * DD, pe_b + DD, attnf);

    gemm_ln<256, false, true><<<MM / 64, 512, 0, stream>>>(
        (const bf16x8*)attnf, (const bf16x8*)(WOF + 65536), xmid, xout0, nullptr,
        ln2_g + DD, ln2_b + DD, (unsigned short*)xnf8);

    gemm_gelu_f8<<<2048, 256, 0, stream>>>(
        xnf8, W1F8 + 262144, geluf, b1 + DFF_, 1024);

    // final FFN2: XCD-swizzled, 64x128 tiles, 1D grid 512
    gemm_frag64<1024, 256, true, true><<<512, 256, 0, stream>>>(
        (const bf16x8*)geluf, (const bf16x8*)(W2F + 262144), (float*)d_out, xmid,
        b2 + DD);
}

// Round 14
// 292.872 us; speedup vs baseline: 1.0865x; 1.0501x over previous
//
#include <hip/hip_runtime.h>
#include <hip/hip_bf16.h>
#include <stdint.h>

#define MM 16384
#define DD 256
#define HH 4
#define KK 16
#define DFF_ 1024

typedef __attribute__((ext_vector_type(8))) short bf16x8;
typedef __attribute__((ext_vector_type(16))) float f32x16;
typedef __attribute__((ext_vector_type(2))) float f32x2;

__device__ __forceinline__ unsigned short f2bf(float f) {
    unsigned u = __builtin_bit_cast(unsigned, f);
    unsigned r = u + 0x7fffu + ((u >> 16) & 1u);
    return (unsigned short)(r >> 16);
}
__device__ __forceinline__ float bf2f(unsigned short h) {
    unsigned u = ((unsigned)h) << 16;
    return __builtin_bit_cast(float, u);
}

// ---------------------------------------------------------------------------
// Fragment layouts (bf16 16B chunks / fp8 8B chunks of 8 elems):
// A-frag (row m, k): chunk = ((m>>5)*(KD/16) + (k>>4))*64 + ((k>>3)&1)*32 + (m&31)
// v_mfma 32x32x16 C/D: col=lane&31, row=(reg&3)+8*(reg>>2)+4*(lane>>5)
// NOTE (R14): TLP lever. R15: 64-col min B-reuse. R16-R20: ~180TF GEMM wall
//   survives occupancy/pipeline/in-flight/staging/fusion/XCD/bytes(R21 fp8
//   -5% only). Per-GEMM optimization exhausted.
// NOTE (R22/R23): block-tail MEGAFUSION (R23 = resubmit of R22; container
//   infra failed twice, audit found no defect -- same as R13 flake).
//   Chain Wo->LN2->FFN1->gelu->FFN2(+resid)->LN1' is 64-row-strip-local;
//   fp8 intermediates fit LDS (xn8 16KB + gelu8 64KB + pads = 115.5KB).
//   P1 Wo+resid (resid slice kept in REGISTERS for P3) + LN2 -> xn8 LDS;
//   P2 FFN1 fp8 (A=LDS, B=W1F8 x32) + gelu -> gelu8 LDS (x16);
//   P3 FFN2 fp8 (A=LDS, B=W2F8 x16, descale 1/256) + reg-resid + b2
//      -> TAIL? d_out : (xout + LN1' -> xnf frags).
//   Removes geluf 128MB RT, xn 16MB RT, xmid 64MB RT; 12 -> 8 dispatches.
// ---------------------------------------------------------------------------

// wfrag bytes: WQF@0 (2x131072B), KVF@262144 (2x262144B), WOF@786432
// (2x131072B); W1F8 fp8 x32 @3145728 (2x262144B); W2F8 fp8 x16 @3670016
// (2x262144B). Total exactly 4MB.
__global__ __launch_bounds__(256) void prep_weights(
        const float* __restrict__ Wq, const float* __restrict__ Wk,
        const float* __restrict__ Wv, const float* __restrict__ Wo,
        const float* __restrict__ W1, const float* __restrict__ W2,
        unsigned short* __restrict__ wf) {
    int t = blockIdx.x * blockDim.x + threadIdx.x;
    const float* src; unsigned short* dst = nullptr;
    int kd, lg, rem, blk, e, sect;
    if (t < 131072) { sect = 0; rem = t; blk = rem >> 16; e = rem & 65535;
        src = Wq; dst = wf + blk * 65536; kd = 256; lg = 8; }
    else if (t < 262144) { sect = 1; rem = t - 131072; blk = rem >> 16; e = rem & 65535;
        src = Wk; dst = wf + 131072 + blk * 131072; kd = 256; lg = 8; }
    else if (t < 393216) { sect = 2; rem = t - 262144; blk = rem >> 16; e = rem & 65535;
        src = Wv; dst = wf + 131072 + blk * 131072; kd = 256; lg = 8; }
    else if (t < 524288) { sect = 0; rem = t - 393216; blk = rem >> 16; e = rem & 65535;
        src = Wo; dst = wf + 393216 + blk * 65536; kd = 256; lg = 8; }
    else if (t < 1048576) { sect = 3; rem = t - 524288; blk = rem >> 18; e = rem & 262143;
        src = W1; kd = 256; lg = 10; }
    else if (t < 1572864) { sect = 4; rem = t - 1048576; blk = rem >> 18; e = rem & 262143;
        src = W2; kd = 1024; lg = 8; }
    else return;
    int k = e >> lg;
    int n = e & ((1 << lg) - 1);
    if (sect == 1) n = (n >> 2) * 8 + (n & 3);
    else if (sect == 2) n = (n >> 2) * 8 + 4 + (n & 3);
    float v = src[(size_t)blk * kd * (1 << lg) + e];
    int off = ((n >> 5) * (kd >> 4) + (k >> 4)) * 512 + (((k >> 3) & 1) * 32 + (n & 31)) * 8 + (k & 7);
    if (sect == 3) {
        unsigned char* d8 = ((unsigned char*)wf) + 3145728 + blk * 262144;
        float vs = v * 32.0f;
        d8[off] = (unsigned char)(__builtin_amdgcn_cvt_pk_fp8_f32(vs, vs, 0, false) & 0xff);
    } else if (sect == 4) {
        unsigned char* d8 = ((unsigned char*)wf) + 3670016 + blk * 262144;
        float vs = v * 16.0f;
        d8[off] = (unsigned char)(__builtin_amdgcn_cvt_pk_fp8_f32(vs, vs, 0, false) & 0xff);
    } else {
        dst[off] = f2bf(v);
    }
}

// 3 slices: y=0: LN(xa)->outln; y=1: conv(xa)->outca; y=2: conv(xb)->outcb
__global__ __launch_bounds__(256) void ln3_to_frag(
        const float* __restrict__ xa, const float* __restrict__ g,
        const float* __restrict__ b, const float* __restrict__ xb,
        unsigned short* __restrict__ outln, unsigned short* __restrict__ outca,
        unsigned short* __restrict__ outcb) {
    int y = blockIdx.y;
    const float* x = (y == 2) ? xb : xa;
    unsigned short* out = (y == 0) ? outln : (y == 1 ? outca : outcb);
    int apply_ln = (y == 0);
    int wave = threadIdx.x >> 6, lane = threadIdx.x & 63;
    int m = blockIdx.x * 4 + wave;
    const float4 xv = reinterpret_cast<const float4*>(x + (size_t)m * DD)[lane];
    float vals[4] = {xv.x, xv.y, xv.z, xv.w};
    int k0 = lane * 4;
    if (apply_ln) {
        float s = vals[0] + vals[1] + vals[2] + vals[3];
        float sq = vals[0]*vals[0] + vals[1]*vals[1] + vals[2]*vals[2] + vals[3]*vals[3];
        for (int o = 32; o; o >>= 1) { s += __shfl_xor(s, o, 64); sq += __shfl_xor(sq, o, 64); }
        float mean = s * (1.0f / DD);
        float var = sq * (1.0f / DD) - mean * mean;
        float rs = rsqrtf(var + 1e-5f);
        #pragma unroll
        for (int c = 0; c < 4; ++c)
            vals[c] = (vals[c] - mean) * rs * g[k0 + c] + b[k0 + c];
    }
    int chunk = ((m >> 5) * (DD >> 4) + (k0 >> 4)) * 64 + ((k0 >> 3) & 1) * 32 + (m & 31);
    ushort4 o4 = make_ushort4(f2bf(vals[0]), f2bf(vals[1]), f2bf(vals[2]), f2bf(vals[3]));
    *reinterpret_cast<ushort4*>(out + (size_t)chunk * 8 + (k0 & 7)) = o4;
}

template <int KG>
__device__ __forceinline__ void compute_tile(
        const bf16x8* __restrict__ a0, const bf16x8* __restrict__ a1,
        const bf16x8* __restrict__ b0, const bf16x8* __restrict__ b1,
        f32x16 acc[2][2]) {
    #pragma unroll 4
    for (int g = 0; g < KG; ++g) {
        bf16x8 av0 = a0[g * 64];
        bf16x8 av1 = a1[g * 64];
        bf16x8 bv0 = b0[g * 64];
        bf16x8 bv1 = b1[g * 64];
        acc[0][0] = __builtin_amdgcn_mfma_f32_32x32x16_bf16(av0, bv0, acc[0][0], 0, 0, 0);
        acc[0][1] = __builtin_amdgcn_mfma_f32_32x32x16_bf16(av0, bv1, acc[0][1], 0, 0, 0);
        acc[1][0] = __builtin_amdgcn_mfma_f32_32x32x16_bf16(av1, bv0, acc[1][0], 0, 0, 0);
        acc[1][1] = __builtin_amdgcn_mfma_f32_32x32x16_bf16(av1, bv1, acc[1][1], 0, 0, 0);
    }
}

// R20 form: fused Q + KV projections with XCD swizzle. 128x128 wg tiles.
__global__ __launch_bounds__(256) void gemm_qkv(
        const bf16x8* __restrict__ Aq, const bf16x8* __restrict__ Akv,
        const bf16x8* __restrict__ Bq, const bf16x8* __restrict__ Bkv,
        unsigned short* __restrict__ qout, unsigned char* __restrict__ kvout) {
    constexpr int KG = 16;
    int wave = threadIdx.x >> 6, lane = threadIdx.x & 63;
    int wm = wave & 1, wn = wave >> 1;
    int id = blockIdx.x;
    int xcd = id & 7, slot = id >> 3;
    int bx = 16 * xcd + (slot & 15);
    int y = slot >> 4;
    bool isQ = y < 2;
    const bf16x8* A = isQ ? Aq : Akv;
    const bf16x8* B = isQ ? Bq : Bkv;
    int n0 = (isQ ? y : y - 2) * 128 + wn * 64;
    int m0 = bx * 128 + wm * 64;
    const bf16x8* a0 = A + ((size_t)(m0 >> 5) * KG) * 64 + lane;
    const bf16x8* a1 = a0 + (size_t)KG * 64;
    const bf16x8* b0 = B + ((size_t)(n0 >> 5) * KG) * 64 + lane;
    const bf16x8* b1 = b0 + (size_t)KG * 64;
    f32x16 acc[2][2] = {};
    compute_tile<KG>(a0, a1, b0, b1, acc);
    int col = lane & 31, rq = (lane >> 5) * 4;
    #pragma unroll
    for (int i = 0; i < 2; ++i)
    #pragma unroll
    for (int j = 0; j < 2; ++j)
    #pragma unroll
    for (int r = 0; r < 16; ++r) {
        int row = (r & 3) + 8 * (r >> 2) + rq;
        int m = m0 + i * 32 + row;
        int n = n0 + j * 32 + col;
        float v = acc[i][j][r];
        if (isQ) qout[(size_t)m * 256 + n] = f2bf(v);
        else kvout[(size_t)m * 512 + n] =
            (unsigned char)(__builtin_amdgcn_cvt_pk_fp8_f32(v, v, 0, false) & 0xff);
    }
}

// butterfly reduce-scatter stage: N slots -> N/2 slots (xor-butterfly).
template <int O, int N>
__device__ __forceinline__ void redstage(float* a, int lane) {
    int sel = lane & O;
    #pragma unroll
    for (int u = 0; u < N / 2; ++u) {
        float lo = a[2 * u], hi = a[2 * u + 1];
        float keep = sel ? hi : lo;
        float send = sel ? lo : hi;
        a[u] = keep + __shfl_xor(send, O, 64);
    }
}

// R22 megakernel: per 64-row strip, 512 thr / 8 waves (2m x 4n of 32x64).
// P1: Wo-GEMM(bf16) + resid(kept in regs) + LN2 -> xn8 LDS (fp8).
// P2: FFN1 fp8 (A=xn8 LDS, B=W1F8 x32, descale 1/32) + gelu -> gelu8 LDS (x16).
// P3: FFN2 fp8 (A=gelu8 LDS, B=W2F8 x16, descale 1/256) + b2 + reg-resid;
//     TAIL=1: -> d_out.  TAIL=0: -> xout + LN1' -> xnf bf16 frags.
template <bool TAIL>
__global__ __launch_bounds__(512) void mega_tail(
        const bf16x8* __restrict__ A, const bf16x8* __restrict__ Bo,
        const float* __restrict__ resid,
        const float* __restrict__ ln2g, const float* __restrict__ ln2b,
        const unsigned char* __restrict__ B1_8, const float* __restrict__ b1,
        const unsigned char* __restrict__ B2_8, const float* __restrict__ b2,
        const float* __restrict__ ln1g, const float* __restrict__ ln1b,
        float* __restrict__ xout, unsigned short* __restrict__ xnf_out) {
    constexpr int KG = 16;
    __shared__ float pstat[4][64][2];
    __shared__ float stats[64][2];
    __shared__ float tlds[8][32 * 33];
    __shared__ alignas(16) unsigned char xn8[2][8192];    // [mgrp][16 kgrp *64*8]
    __shared__ alignas(16) unsigned char gelu8[2][32768]; // [mgrp][64 kgrp *64*8]
    int wave = threadIdx.x >> 6, lane = threadIdx.x & 63;
    int wm = wave >> 2, wn = wave & 3;
    int m0 = blockIdx.x * 64;
    int mw = m0 + wm * 32;
    int col = lane & 31, rq = (lane >> 5) * 4;

    // ---------------- P1: Wo GEMM (bf16) ----------------
    f32x16 xm[2];
    {
        int n0 = wn * 64;
        const bf16x8* a0 = A + ((size_t)(mw >> 5) * KG) * 64 + lane;
        const bf16x8* b0 = Bo + ((size_t)(n0 >> 5) * KG) * 64 + lane;
        const bf16x8* b1o = b0 + (size_t)KG * 64;
        f32x16 acc[2] = {};
        #pragma unroll 4
        for (int g = 0; g < KG; ++g) {
            bf16x8 av = a0[g * 64];
            bf16x8 bv0 = b0[g * 64];
            bf16x8 bv1 = b1o[g * 64];
            acc[0] = __builtin_amdgcn_mfma_f32_32x32x16_bf16(av, bv0, acc[0], 0, 0, 0);
            acc[1] = __builtin_amdgcn_mfma_f32_32x32x16_bf16(av, bv1, acc[1], 0, 0, 0);
        }
        // + resid -> xm (registers; P3 reads the exact same slice)
        #pragma unroll
        for (int j = 0; j < 2; ++j)
        #pragma unroll
        for (int r = 0; r < 16; ++r) {
            int row = (r & 3) + 8 * (r >> 2) + rq;
            int m = mw + row;
            int n = n0 + j * 32 + col;
            xm[j][r] = acc[j][r] + resid[(size_t)m * DD + n];
        }
        // LN2 stats
        {
            float ps[16];
            #pragma unroll
            for (int r = 0; r < 16; ++r) ps[r] = xm[0][r] + xm[1][r];
            redstage<1, 16>(ps, lane);
            redstage<2, 8>(ps, lane);
            redstage<4, 4>(ps, lane);
            redstage<8, 2>(ps, lane);
            float sum64 = ps[0] + __shfl_xor(ps[0], 16, 64);
            float qs[16];
            #pragma unroll
            for (int r = 0; r < 16; ++r) {
                float a2 = xm[0][r], b2v = xm[1][r];
                qs[r] = a2 * a2 + b2v * b2v;
            }
            redstage<1, 16>(qs, lane);
            redstage<2, 8>(qs, lane);
            redstage<4, 4>(qs, lane);
            redstage<8, 2>(qs, lane);
            float sq64 = qs[0] + __shfl_xor(qs[0], 16, 64);
            int slot = lane & 15;
            int ROW = wm * 32 + (slot & 3) + 8 * (slot >> 2) + rq;
            if ((lane & 16) == 0)
                *reinterpret_cast<float2*>(&pstat[wn][ROW][0]) = make_float2(sum64, sq64);
        }
        __syncthreads();
        if (threadIdx.x < 64) {
            int R = threadIdx.x;
            float s = 0.0f, sq = 0.0f;
            #pragma unroll
            for (int w = 0; w < 4; ++w) {
                float2 p = *reinterpret_cast<float2*>(&pstat[w][R][0]);
                s += p.x; sq += p.y;
            }
            float mean = s * (1.0f / DD);
            float var = sq * (1.0f / DD) - mean * mean;
            float rstd = rsqrtf(var + 1e-5f);
            *reinterpret_cast<float2*>(&stats[R][0]) = make_float2(mean, rstd);
        }
        __syncthreads();
        // normalize + pack fp8 -> xn8 LDS
        float* wlds = &tlds[wave][0];
        float mean_r[16], rstd_r[16];
        #pragma unroll
        for (int r = 0; r < 16; ++r) {
            int row = (r & 3) + 8 * (r >> 2) + rq;
            float2 st = *reinterpret_cast<float2*>(&stats[wm * 32 + row][0]);
            mean_r[r] = st.x; rstd_r[r] = st.y;
        }
        for (int j = 0; j < 2; ++j) {
            float gj = ln2g[n0 + j * 32 + col];
            float bj = ln2b[n0 + j * 32 + col];
            #pragma unroll
            for (int r = 0; r < 16; ++r) {
                int row = (r & 3) + 8 * (r >> 2) + rq;
                float v = (xm[j][r] - mean_r[r]) * rstd_r[r] * gj + bj;
                wlds[row * 33 + col] = v;
            }
            #pragma unroll
            for (int it = 0; it < 2; ++it) {
                int task = lane + it * 64;
                int row = task >> 2, cc = task & 3;
                int k = n0 + j * 32 + cc * 8;
                float* p = &wlds[row * 33 + cc * 8];
                unsigned w0 = __builtin_amdgcn_cvt_pk_fp8_f32(p[0], p[1], 0, false);
                w0 = __builtin_amdgcn_cvt_pk_fp8_f32(p[2], p[3], w0, true);
                unsigned w1 = __builtin_amdgcn_cvt_pk_fp8_f32(p[4], p[5], 0, false);
                w1 = __builtin_amdgcn_cvt_pk_fp8_f32(p[6], p[7], w1, true);
                int lch = (k >> 4) * 64 + ((k >> 3) & 1) * 32 + row;
                *reinterpret_cast<uint2*>(&xn8[wm][lch * 8]) = make_uint2(w0, w1);
            }
        }
    }
    __syncthreads();

    // ---------------- P2: FFN1 fp8 + gelu -> gelu8 LDS ----------------
    {
        const unsigned char* la8 = &xn8[wm][lane * 8];
        #pragma unroll
        for (int h = 0; h < 2; ++h) {
            int nw2 = h * 512 + wn * 128;
            const uint2* bb = (const uint2*)B1_8 + ((size_t)(nw2 >> 5) * KG) * 64 + lane;
            f32x16 acc4[4] = {};
            #pragma unroll 2
            for (int g = 0; g < KG; ++g) {
                long av = __builtin_bit_cast(long, *reinterpret_cast<const uint2*>(la8 + g * 512));
                long bv0 = __builtin_bit_cast(long, bb[g * 64]);
                long bv1 = __builtin_bit_cast(long, bb[(KG + g) * 64]);
                long bv2 = __builtin_bit_cast(long, bb[(2 * KG + g) * 64]);
                long bv3 = __builtin_bit_cast(long, bb[(3 * KG + g) * 64]);
                acc4[0] = __builtin_amdgcn_mfma_f32_32x32x16_fp8_fp8(av, bv0, acc4[0], 0, 0, 0);
                acc4[1] = __builtin_amdgcn_mfma_f32_32x32x16_fp8_fp8(av, bv1, acc4[1], 0, 0, 0);
                acc4[2] = __builtin_amdgcn_mfma_f32_32x32x16_fp8_fp8(av, bv2, acc4[2], 0, 0, 0);
                acc4[3] = __builtin_amdgcn_mfma_f32_32x32x16_fp8_fp8(av, bv3, acc4[3], 0, 0, 0);
            }
            float* wlds = &tlds[wave][0];
            for (int j = 0; j < 4; ++j) {
                #pragma unroll
                for (int r = 0; r < 16; ++r) {
                    int row = (r & 3) + 8 * (r >> 2) + rq;
                    int n = nw2 + j * 32 + col;
                    float v = acc4[j][r] * (1.0f / 32.0f) + b1[n];
                    float arg = v * (1.5957691216f + 0.0713548163f * v * v);
                    v = v * __frcp_rn(1.0f + __expf(-arg));
                    wlds[row * 33 + col] = v;
                }
                #pragma unroll
                for (int it = 0; it < 2; ++it) {
                    int task = lane + it * 64;
                    int row = task >> 2, cc = task & 3;
                    int k = nw2 + j * 32 + cc * 8;
                    float* p = &wlds[row * 33 + cc * 8];
                    unsigned w0 = __builtin_amdgcn_cvt_pk_fp8_f32(p[0] * 16.f, p[1] * 16.f, 0, false);
                    w0 = __builtin_amdgcn_cvt_pk_fp8_f32(p[2] * 16.f, p[3] * 16.f, w0, true);
                    unsigned w1 = __builtin_amdgcn_cvt_pk_fp8_f32(p[4] * 16.f, p[5] * 16.f, 0, false);
                    w1 = __builtin_amdgcn_cvt_pk_fp8_f32(p[6] * 16.f, p[7] * 16.f, w1, true);
                    int lch = (k >> 4) * 64 + ((k >> 3) & 1) * 32 + row;
                    *reinterpret_cast<uint2*>(&gelu8[wm][lch * 8]) = make_uint2(w0, w1);
                }
            }
        }
    }
    __syncthreads();

    // ---------------- P3: FFN2 fp8 (K=1024) ----------------
    {
        constexpr int KG2 = 64;
        int n0 = wn * 64;
        const unsigned char* lg8 = &gelu8[wm][lane * 8];
        const uint2* bp0 = (const uint2*)B2_8 + ((size_t)(n0 >> 5) * KG2) * 64 + lane;
        const uint2* bp1 = bp0 + (size_t)KG2 * 64;
        f32x16 acc[2] = {};
        #pragma unroll 4
        for (int g = 0; g < KG2; ++g) {
            long av = __builtin_bit_cast(long, *reinterpret_cast<const uint2*>(lg8 + g * 512));
            long bv0 = __builtin_bit_cast(long, bp0[g * 64]);
            long bv1 = __builtin_bit_cast(long, bp1[g * 64]);
            acc[0] = __builtin_amdgcn_mfma_f32_32x32x16_fp8_fp8(av, bv0, acc[0], 0, 0, 0);
            acc[1] = __builtin_amdgcn_mfma_f32_32x32x16_fp8_fp8(av, bv1, acc[1], 0, 0, 0);
        }
        // v = acc/256 + b2 + reg-resid
        #pragma unroll
        for (int j = 0; j < 2; ++j)
        #pragma unroll
        for (int r = 0; r < 16; ++r) {
            int n = n0 + j * 32 + col;
            acc[j][r] = acc[j][r] * (1.0f / 256.0f) + b2[n] + xm[j][r];
        }
        if constexpr (TAIL) {
            #pragma unroll
            for (int j = 0; j < 2; ++j)
            #pragma unroll
            for (int r = 0; r < 16; ++r) {
                int row = (r & 3) + 8 * (r >> 2) + rq;
                int m = mw + row;
                int n = n0 + j * 32 + col;
                xout[(size_t)m * DD + n] = acc[j][r];
            }
        } else {
            // write xout + LN1' -> bf16 frags (for next block's Q-proj)
            #pragma unroll
            for (int j = 0; j < 2; ++j)
            #pragma unroll
            for (int r = 0; r < 16; ++r) {
                int row = (r & 3) + 8 * (r >> 2) + rq;
                int m = mw + row;
                int n = n0 + j * 32 + col;
                xout[(size_t)m * DD + n] = acc[j][r];
            }
            {
                float ps[16];
                #pragma unroll
                for (int r = 0; r < 16; ++r) ps[r] = acc[0][r] + acc[1][r];
                redstage<1, 16>(ps, lane);
                redstage<2, 8>(ps, lane);
                redstage<4, 4>(ps, lane);
                redstage<8, 2>(ps, lane);
                float sum64 = ps[0] + __shfl_xor(ps[0], 16, 64);
                float qs[16];
                #pragma unroll
                for (int r = 0; r < 16; ++r) {
                    float a2 = acc[0][r], b2v = acc[1][r];
                    qs[r] = a2 * a2 + b2v * b2v;
                }
                redstage<1, 16>(qs, lane);
                redstage<2, 8>(qs, lane);
                redstage<4, 4>(qs, lane);
                redstage<8, 2>(qs, lane);
                float sq64 = qs[0] + __shfl_xor(qs[0], 16, 64);
                int slot = lane & 15;
                int ROW = wm * 32 + (slot & 3) + 8 * (slot >> 2) + rq;
                if ((lane & 16) == 0)
                    *reinterpret_cast<float2*>(&pstat[wn][ROW][0]) = make_float2(sum64, sq64);
            }
            __syncthreads();
            if (threadIdx.x < 64) {
                int R = threadIdx.x;
                float s = 0.0f, sq = 0.0f;
                #pragma unroll
                for (int w = 0; w < 4; ++w) {
                    float2 p = *reinterpret_cast<float2*>(&pstat[w][R][0]);
                    s += p.x; sq += p.y;
                }
                float mean = s * (1.0f / DD);
                float var = sq * (1.0f / DD) - mean * mean;
                float rstd = rsqrtf(var + 1e-5f);
                *reinterpret_cast<float2*>(&stats[R][0]) = make_float2(mean, rstd);
            }
            __syncthreads();
            float* wlds = &tlds[wave][0];
            float mean_r[16], rstd_r[16];
            #pragma unroll
            for (int r = 0; r < 16; ++r) {
                int row = (r & 3) + 8 * (r >> 2) + rq;
                float2 st = *reinterpret_cast<float2*>(&stats[wm * 32 + row][0]);
                mean_r[r] = st.x; rstd_r[r] = st.y;
            }
            for (int j = 0; j < 2; ++j) {
                float gj = ln1g[n0 + j * 32 + col];
                float bj = ln1b[n0 + j * 32 + col];
                #pragma unroll
                for (int r = 0; r < 16; ++r) {
                    int row = (r & 3) + 8 * (r >> 2) + rq;
                    float v = (acc[j][r] - mean_r[r]) * rstd_r[r] * gj + bj;
                    wlds[row * 33 + col] = v;
                }
                #pragma unroll
                for (int it = 0; it < 2; ++it) {
                    int task = lane + it * 64;
                    int row = task >> 2, cc = task & 3;
                    int m = mw + row;
                    int k = n0 + j * 32 + cc * 8;
                    float* p = &wlds[row * 33 + cc * 8];
                    unsigned short us[8];
                    #pragma unroll
                    for (int e = 0; e < 8; ++e) us[e] = f2bf(p[e]);
                    int chunk = ((m >> 5) * (DD >> 4) + (k >> 4)) * 64 + ((k >> 3) & 1) * 32 + (m & 31);
                    *reinterpret_cast<uint4*>(xnf_out + (size_t)chunk * 8) = *reinterpret_cast<uint4*>(us);
                }
            }
        }
    }
}

// One wave per point. lane = h*16+s; dims d0 = h*64+s*4.
__global__ __launch_bounds__(256) void attn_kernel(
        const unsigned short* __restrict__ q, const unsigned char* __restrict__ kv,
        const float* __restrict__ coord, const float* __restrict__ ctx_coord,
        const int* __restrict__ knn,
        const float* __restrict__ pe_w, const float* __restrict__ pe_b,
        unsigned short* __restrict__ out_frag) {
    int wave = threadIdx.x >> 6, lane = threadIdx.x & 63;
    int m = blockIdx.x * 4 + wave;
    int s = lane & 15;
    int d0 = (lane >> 4) * 64 + s * 4;

    ushort4 qv4 = *reinterpret_cast<const ushort4*>(q + (size_t)m * DD + d0);
    float qx = bf2f(qv4.x), qy = bf2f(qv4.y), qz = bf2f(qv4.z), qw = bf2f(qv4.w);
    float4 pw0 = *reinterpret_cast<const float4*>(pe_w + d0);
    float4 pw1 = *reinterpret_cast<const float4*>(pe_w + DD + d0);
    float4 pw2 = *reinterpret_cast<const float4*>(pe_w + 2 * DD + d0);
    float4 pbv = *reinterpret_cast<const float4*>(pe_b + d0);

    float cx = coord[m * 3], cy = coord[m * 3 + 1], cz = coord[m * 3 + 2];
    int myidx = knn[(size_t)m * KK + s];
    int icm = myidx < 0 ? 0 : myidx;
    float rx = cx - ctx_coord[icm * 3];
    float ry = cy - ctx_coord[icm * 3 + 1];
    float rz = cz - ctx_coord[icm * 3 + 2];

    float t0 = qx * pw0.x + qy * pw0.y + qz * pw0.z + qw * pw0.w;
    float t1 = qx * pw1.x + qy * pw1.y + qz * pw1.z + qw * pw1.w;
    float t2 = qx * pw2.x + qy * pw2.y + qz * pw2.z + qw * pw2.w;
    float t3 = qx * pbv.x + qy * pbv.y + qz * pbv.z + qw * pbv.w;
    #pragma unroll
    for (int o = 1; o < 16; o <<= 1) {
        t0 += __shfl_xor(t0, o, 64);
        t1 += __shfl_xor(t1, o, 64);
        t2 += __shfl_xor(t2, o, 64);
        t3 += __shfl_xor(t3, o, 64);
    }

    float P[KK];
    unsigned vpk[KK];
    #pragma unroll
    for (int j = 0; j < KK; ++j) {
        int ij = __shfl(myidx, j, 64);
        int ic = ij < 0 ? 0 : ij;
        uint2 kvv = *reinterpret_cast<const uint2*>(kv + (size_t)ic * 512 + (d0 >> 2) * 8);
        vpk[j] = kvv.y;
        f32x2 k01 = __builtin_amdgcn_cvt_pk_f32_fp8(kvv.x, false);
        f32x2 k23 = __builtin_amdgcn_cvt_pk_f32_fp8(kvv.x, true);
        P[j] = qx * k01.x + qy * k01.y + qz * k23.x + qw * k23.y;
    }
    redstage<1, 16>(P, lane);
    redstage<2, 8>(P, lane);
    redstage<4, 4>(P, lane);
    redstage<8, 2>(P, lane);
    float corr = rx * t0 + ry * t1 + rz * t2 + t3;
    float sc_own = (myidx >= 0) ? (P[0] + corr) * 0.125f : -1e9f;

    float mx = sc_own;
    mx = fmaxf(mx, __shfl_xor(mx, 1, 64));
    mx = fmaxf(mx, __shfl_xor(mx, 2, 64));
    mx = fmaxf(mx, __shfl_xor(mx, 4, 64));
    mx = fmaxf(mx, __shfl_xor(mx, 8, 64));
    float e = __expf(sc_own - mx);
    float sum = e;
    sum += __shfl_xor(sum, 1, 64);
    sum += __shfl_xor(sum, 2, 64);
    sum += __shfl_xor(sum, 4, 64);
    sum += __shfl_xor(sum, 8, 64);
    float w_own = e * __frcp_rn(sum);

    float wrx = w_own * rx, wry = w_own * ry, wrz = w_own * rz;
    #pragma unroll
    for (int o = 1; o < 16; o <<= 1) {
        wrx += __shfl_xor(wrx, o, 64);
        wry += __shfl_xor(wry, o, 64);
        wrz += __shfl_xor(wrz, o, 64);
    }

    int gbase = lane & 48;
    float ax = 0.f, ay = 0.f, az = 0.f, aw = 0.f;
    #pragma unroll
    for (int j = 0; j < KK; ++j) {
        float wj = __shfl(w_own, gbase + j, 64);
        f32x2 v01 = __builtin_amdgcn_cvt_pk_f32_fp8(vpk[j], false);
        f32x2 v23 = __builtin_amdgcn_cvt_pk_f32_fp8(vpk[j], true);
        ax += wj * v01.x;
        ay += wj * v01.y;
        az += wj * v23.x;
        aw += wj * v23.y;
    }
    ax += wrx * pw0.x + wry * pw1.x + wrz * pw2.x + pbv.x;
    ay += wrx * pw0.y + wry * pw1.y + wrz * pw2.y + pbv.y;
    az += wrx * pw0.z + wry * pw1.z + wrz * pw2.z + pbv.z;
    aw += wrx * pw0.w + wry * pw1.w + wrz * pw2.w + pbv.w;

    ushort4 o4 = make_ushort4(f2bf(ax), f2bf(ay), f2bf(az), f2bf(aw));
    int chunk = ((m >> 5) * (DD >> 4) + (d0 >> 4)) * 64 + ((d0 >> 3) & 1) * 32 + (m & 31);
    *reinterpret_cast<ushort4*>(out_frag + (size_t)chunk * 8 + (d0 & 7)) = o4;
}

extern "C" void kernel_launch(void* const* d_in, const int* in_sizes, int n_in,
                              void* d_out, int out_size, void* d_ws, size_t ws_size,
                              hipStream_t stream) {
    const float* feat_a = (const float*)d_in[0];
    const float* coord_a = (const float*)d_in[1];
    const float* feat_b = (const float*)d_in[2];
    const float* coord_b = (const float*)d_in[3];
    const float* Wq = (const float*)d_in[4];
    const float* Wk = (const float*)d_in[5];
    const float* Wv = (const float*)d_in[6];
    const float* Wo = (const float*)d_in[7];
    const float* ln1_g = (const float*)d_in[8];
    const float* ln1_b = (const float*)d_in[9];
    const float* pe_w = (const float*)d_in[10];
    const float* pe_b = (const float*)d_in[11];
    const float* W1 = (const float*)d_in[12];
    const float* b1 = (const float*)d_in[13];
    const float* W2 = (const float*)d_in[14];
    const float* b2 = (const float*)d_in[15];
    const float* ln2_g = (const float*)d_in[16];
    const float* ln2_b = (const float*)d_in[17];
    const int* knn_a2a = (const int*)d_in[18];
    const int* knn_a2b = (const int*)d_in[19];

    char* ws = (char*)d_ws;
    unsigned short* wfrag = (unsigned short*)ws;                  // 4 MB
    float* xout0 = (float*)(ws + (20ull << 20));                  // 16 MB
    unsigned short* qbuf = (unsigned short*)(ws + (36ull << 20)); // 8 MB
    unsigned char* kvbuf = (unsigned char*)(ws + (52ull << 20));  // 8 MB (fp8)
    unsigned short* xnf = (unsigned short*)(ws + (68ull << 20));  // 8 MB
    unsigned short* ctxfa = (unsigned short*)(ws + (76ull << 20));// 8 MB
    unsigned short* attnf = (unsigned short*)(ws + (84ull << 20));// 8 MB
    unsigned short* ctxfb = (unsigned short*)(ws + (92ull << 20));// 8 MB -> 100 MB

    const unsigned short* WQF = wfrag;
    const unsigned short* KVF = wfrag + 131072;
    const unsigned short* WOF = wfrag + 393216;
    const unsigned char* W1F8 = ((const unsigned char*)wfrag) + 3145728;
    const unsigned char* W2F8 = ((const unsigned char*)wfrag) + 3670016;

    prep_weights<<<(1572864 + 255) / 256, 256, 0, stream>>>(Wq, Wk, Wv, Wo, W1, W2, wfrag);

    // xnf = LN1(feat_a); ctxfa = conv(feat_a); ctxfb = conv(feat_b)
    ln3_to_frag<<<dim3(MM / 4, 3), 256, 0, stream>>>(feat_a, ln1_g, ln1_b, feat_b,
                                                     xnf, ctxfa, ctxfb);

    // ---- block 0: self(a) ----
    gemm_qkv<<<768, 256, 0, stream>>>(
        (const bf16x8*)xnf, (const bf16x8*)ctxfa,
        (const bf16x8*)WQF, (const bf16x8*)KVF, qbuf, kvbuf);

    attn_kernel<<<MM / 4, 256, 0, stream>>>(qbuf, kvbuf, coord_a, coord_a, knn_a2a,
                                            pe_w, pe_b, attnf);

    // Wo+resid+LN2 + FFN1(fp8)+gelu + FFN2(fp8)+resid + LN1' -> xout0 + xnf
    mega_tail<false><<<MM / 64, 512, 0, stream>>>(
        (const bf16x8*)attnf, (const bf16x8*)WOF, feat_a, ln2_g, ln2_b,
        W1F8, b1, W2F8, b2, ln1_g + DD, ln1_b + DD, xout0, xnf);

    // ---- block 1: cross(a,b) ----
    gemm_qkv<<<768, 256, 0, stream>>>(
        (const bf16x8*)xnf, (const bf16x8*)ctxfb,
        (const bf16x8*)(WQF + 65536), (const bf16x8*)(KVF + 131072), qbuf, kvbuf);

    attn_kernel<<<MM / 4, 256, 0, stream>>>(qbuf, kvbuf, coord_a, coord_b, knn_a2b,
                                            pe_w + 3 * DD, pe_b + DD, attnf);

    // Wo+resid+LN2 + FFN1(fp8)+gelu + FFN2(fp8)+resid -> d_out
    mega_tail<true><<<MM / 64, 512, 0, stream>>>(
        (const bf16x8*)attnf, (const bf16x8*)(WOF + 65536), xout0,
        ln2_g + DD, ln2_b + DD, W1F8 + 262144, b1 + DFF_,
        W2F8 + 262144, b2 + DD, nullptr, nullptr, (float*)d_out, nullptr);
}